// Round 1
// 21174.397 us; speedup vs baseline: 1.2521x; 1.2521x over previous
//
#include <hip/hip_runtime.h>

#define SS 500
#define NBLKS 256
#define NSLOT 64
#define DYN_LDS 149888
#define RING 16

typedef __bf16 bf16_t;
typedef bf16_t bf16x8 __attribute__((ext_vector_type(8)));
typedef float floatx4 __attribute__((ext_vector_type(4)));

union ABu { uint4 u4; bf16x8 v; unsigned short us[8]; };

#define MFMA(a,b,c) __builtin_amdgcn_mfma_f32_16x16x32_bf16((a),(b),(c),0,0,0)

__device__ __forceinline__ float b2f(unsigned short u){
  union { unsigned int ui; float f; } x; x.ui = ((unsigned int)u) << 16; return x.f;
}
__device__ __forceinline__ unsigned short f2b(float f){
  union { float f; unsigned int ui; } x; x.f = f;
  unsigned int r = x.ui + 0x7FFFu + ((x.ui >> 16) & 1u);
  return (unsigned short)(r >> 16);
}
__device__ __forceinline__ float sigf(float x){ return 1.f/(1.f + __expf(-x)); }
__device__ __forceinline__ float tanhf_fast(float x){
  x = fminf(fmaxf(x, -15.f), 15.f);
  float e = __expf(2.f*x);
  return (e - 1.f)/(e + 1.f);
}

// write-through store: bypasses/updates past L2, lands at LLC (coherence point).
// This is what lets us drop the per-barrier wbl2/inv fences entirely.
__device__ __forceinline__ void st_sc(unsigned short* p, unsigned short v){
  unsigned int w32 = v;
  asm volatile("global_store_short %0, %1, off sc0 sc1" :: "v"(p), "v"(w32) : "memory");
}

// ---- grid barrier v5: NO agent fences. Cross-block data goes through sc0/sc1
// write-through stores (st_sc), so visibility only needs vmcnt(0) before the
// arrival atomic. Consumers read via plain cached loads from ring-rotated
// buffers (fresh addresses each step); a full acquire-inv runs every 8 steps
// to clear stale copies before ring slots are reused. L2 stays hot with the
// read-only weights/enc/pm across all 500 steps.
__device__ __forceinline__ void gbar(unsigned int* slots, unsigned int* flag,
                                     unsigned int ep, int is_master){
  asm volatile("s_waitcnt vmcnt(0)" ::: "memory");   // drain this wave's sc1 stores
  __syncthreads();
  if (threadIdx.x == 0){
    __hip_atomic_fetch_add(&slots[(blockIdx.x & (NSLOT-1)) * 32], 1u,
                           __ATOMIC_RELAXED, __HIP_MEMORY_SCOPE_AGENT);
  }
  if (is_master){
    if (threadIdx.x < 64){
      for(;;){
        unsigned int v = __hip_atomic_load(&slots[threadIdx.x * 32],
                                           __ATOMIC_RELAXED, __HIP_MEMORY_SCOPE_AGENT);
        int t = (int)v;
        t += __shfl_xor(t, 1);  t += __shfl_xor(t, 2);  t += __shfl_xor(t, 4);
        t += __shfl_xor(t, 8);  t += __shfl_xor(t, 16); t += __shfl_xor(t, 32);
        if ((unsigned int)t >= ep * NBLKS) break;
        __builtin_amdgcn_s_sleep(1);
      }
      __hip_atomic_store(&flag[threadIdx.x * 32], ep,
                         __ATOMIC_RELAXED, __HIP_MEMORY_SCOPE_AGENT);
    }
  } else {
    if (threadIdx.x == 0){
      unsigned int* myf = &flag[(blockIdx.x & (NSLOT-1)) * 32];
      while (__hip_atomic_load(myf, __ATOMIC_RELAXED, __HIP_MEMORY_SCOPE_AGENT) < ep)
        __builtin_amdgcn_s_sleep(2);
    }
  }
  __syncthreads();
  asm volatile("" ::: "memory");   // compiler fence: no load hoisting above poll
}

// ---------------- prep kernels ----------------

__global__ void k_pm(const float* __restrict__ enc, const float* __restrict__ ew,
                     const float* __restrict__ eb, unsigned short* __restrict__ pmb){
  int id = blockIdx.x*256 + threadIdx.x;
  if (id >= 64*200*128) return;
  int h = id & 127; int bt = id >> 7;
  const float* er = enc + (size_t)bt*256;
  const float* wr = ew + (size_t)h*256;
  float a0=eb[h], a1=0.f, a2=0.f, a3=0.f;
  for (int k=0;k<256;k+=4){
    a0 += er[k]*wr[k]; a1 += er[k+1]*wr[k+1]; a2 += er[k+2]*wr[k+2]; a3 += er[k+3]*wr[k+3];
  }
  pmb[id] = f2b((a0+a1)+(a2+a3));
}

__global__ void k_encb(const float* __restrict__ enc, unsigned short* __restrict__ encb){
  int id = blockIdx.x*256 + threadIdx.x;
  if (id >= 64*200*256) return;
  encb[id] = f2b(enc[id]);
}

__global__ void k_w2f(const float* __restrict__ attw, const float* __restrict__ convw,
                      unsigned short* __restrict__ w2f){
  __shared__ float s_w2[128*31];
  int tid = threadIdx.x;
  for (int i = tid; i < 128*31; i += 256){
    int h = i / 31, k = i % 31;
    float v = 0.f;
    for (int c=0;c<32;++c) v += attw[h*32+c]*convw[c*31+k];
    s_w2[i] = v;
  }
  __syncthreads();
  for (int i = tid; i < 512; i += 256){
    int nt = i >> 6, lane = i & 63;
    int h = nt*16 + (lane&15);
    for (int j=0;j<8;++j){
      int k = (lane>>4)*8 + j;
      w2f[(nt*64+lane)*8+j] = f2b(k < 31 ? s_w2[h*31+k] : 0.f);
    }
  }
}

__global__ void k_packlstm(const float* __restrict__ wih, const float* __restrict__ whh,
                           unsigned short* __restrict__ dst, int Kih, int NKS){
  int id = blockIdx.x*256 + threadIdx.x;
  if (id >= 128*NKS*64) return;
  int lane = id & 63; int t = id >> 6; int cu = t / NKS;
  for (int nt=0; nt<2; ++nt){
    int n = nt*16 + (lane&15);
    int du = n>>2, g = n&3;
    int row = g*1024 + cu*8 + du;
    for (int j=0;j<8;++j){
      int k = (t % NKS)*32 + ((lane>>4)*8) + j;
      float v = (k < Kih) ? wih[(size_t)row*Kih + k] : whh[(size_t)row*1024 + (k - Kih)];
      dst[((size_t)(t*2+nt)*64 + lane)*8 + j] = f2b(v);
    }
  }
}

__global__ void k_bias(const float* bi0,const float* bh0,const float* bi1,const float* bh1,
                       float* b0p, float* b1p){
  int id = blockIdx.x*256 + threadIdx.x;
  if (id >= 4096) return;
  int cu = id>>5, n = id&31, du = n>>2, g = n&3;
  int row = g*1024 + cu*8 + du;
  b0p[id] = bi0[row] + bh0[row];
  b1p[id] = bi1[row] + bh1[row];
}

__global__ void k_packgen(const float* __restrict__ src, unsigned short* __restrict__ dst,
                          int N, int K){
  int tot = (N/16)*(K/32)*64;
  int id = blockIdx.x*256 + threadIdx.x;
  if (id >= tot) return;
  int lane = id & 63; int t = id >> 6;
  int nks = K/32;
  int n = (t / nks)*16 + (lane&15);
  for (int j=0;j<8;++j){
    int k = (t % nks)*32 + (lane>>4)*8 + j;
    dst[((size_t)t*64 + lane)*8 + j] = f2b(src[(size_t)n*K + k]);
  }
}

__global__ void k_woutp(const float* __restrict__ fw, const float* __restrict__ pw,
                        unsigned short* __restrict__ dst){
  int id = blockIdx.x*256 + threadIdx.x;
  if (id >= 11*40*64) return;
  int lane = id & 63; int t = id >> 6;
  int n = (t/40)*16 + (lane&15);
  for (int j=0;j<8;++j){
    int k = (t%40)*32 + (lane>>4)*8 + j;
    float v = 0.f;
    if (n < 160) v = fw[(size_t)n*1280 + k];
    else if (n < 162) v = pw[(size_t)(n-160)*1280 + k];
    dst[((size_t)t*64 + lane)*8 + j] = f2b(v);
  }
}

__global__ void k_pre1(const float* __restrict__ ftgt, const unsigned short* __restrict__ w0p,
                       const float* __restrict__ b0, unsigned short* __restrict__ C1){
  int mt = blockIdx.x;
  int tid = threadIdx.x, w = tid>>6, L = tid&63, ccol = L&15, q = L>>4;
  int sb0 = mt*16; int s = sb0 >> 6; int b0r = sb0 & 63;
  floatx4 z = {0.f,0.f,0.f,0.f};
  floatx4 acc[4] = {z,z,z,z};
  for (int ks=0; ks<5; ++ks){
    ABu av;
    if (s == 0){ av.u4.x=0; av.u4.y=0; av.u4.z=0; av.u4.w=0; }
    else {
      int b = b0r + ccol;
      for (int j=0;j<8;++j){
        int jj = ks*32 + q*8 + j;
        av.us[j] = f2b(ftgt[(size_t)b*80000 + (size_t)(jj%80)*1000 + (size_t)(s-1)*2 + (jj/80)]);
      }
    }
    for (int i=0;i<4;++i){
      ABu bf; bf.u4 = *(const uint4*)(w0p + ((size_t)((w*4+i)*5 + ks)*64 + L)*8);
      acc[i] = MFMA(av.v, bf.v, acc[i]);
    }
  }
  for (int i=0;i<4;++i){
    int icol = (w*4+i)*16 + ccol;
    float bia = b0[icol];
    for (int r=0;r<4;++r){
      int sb = sb0 + q*4 + r;
      C1[(size_t)sb*256 + icol] = f2b(fmaxf(acc[i][r] + bia, 0.f));
    }
  }
}

__global__ void k_pre2(const unsigned short* __restrict__ C1, const unsigned short* __restrict__ w1p,
                       const float* __restrict__ b1, unsigned short* __restrict__ P){
  int mt = blockIdx.x;
  int tid = threadIdx.x, w = tid>>6, L = tid&63, ccol = L&15, q = L>>4;
  int sb0 = mt*16;
  floatx4 z = {0.f,0.f,0.f,0.f};
  floatx4 acc[4] = {z,z,z,z};
  for (int ks=0; ks<8; ++ks){
    ABu av; av.u4 = *(const uint4*)(C1 + (size_t)(sb0+ccol)*256 + ks*32 + q*8);
    for (int i=0;i<4;++i){
      ABu bf; bf.u4 = *(const uint4*)(w1p + ((size_t)((w*4+i)*8 + ks)*64 + L)*8);
      acc[i] = MFMA(av.v, bf.v, acc[i]);
    }
  }
  for (int i=0;i<4;++i){
    int icol = (w*4+i)*16 + ccol;
    float bia = b1[icol];
    for (int r=0;r<4;++r){
      int sb = sb0 + q*4 + r;
      P[(size_t)sb*256 + icol] = f2b(fmaxf(acc[i][r] + bia, 0.f));
    }
  }
}

// ---------------- persistent decoder ----------------

struct PArgs {
  const int* tlen;
  const float* ww; const float* wwb; const float* probb;
  const unsigned short* pmb; const unsigned short* encb;
  const unsigned short* W2f; const unsigned short* Wdecf;
  const unsigned short* W0p; const unsigned short* W1p;
  const float* b0p; const float* b1p;
  const unsigned short* P; const unsigned short* Woutp;
  unsigned short* xh0; unsigned short* xh1; unsigned short* acbf;
  unsigned int* bar; unsigned int* flag;
  float* dout;
};

__global__ __launch_bounds__(256, 1) void k_decoder(PArgs A)
{
  const int cu = blockIdx.x;
  const int tid = threadIdx.x;
  const int w = tid>>6, L = tid&63;
  const int ccol = L&15, q = L>>4;
  const int is_master = (cu == NBLKS-1);

  extern __shared__ char pool[];
  unsigned short* sW;
  unsigned short* sWOUT = nullptr;
  float* sGB; float* sCST; float* sBIAS;
  if (cu < 128){
    sW    = (unsigned short*)pool;                 // 98304 B
    sWOUT = (unsigned short*)(pool + 98304);       // 40960 B (cu 64..74)
    sGB   = (float*)(pool + 139264);               // 8448 B  (64*33 floats, padded)
    sCST  = (float*)(pool + 147712);               // 2048 B
    sBIAS = (float*)(pool + 149760);               // 128 B
  } else {
    sW    = (unsigned short*)pool;                 // 131072 B
    sGB   = (float*)(pool + 131072);               // 8448 B
    sCST  = (float*)(pool + 139520);               // 2048 B
    sBIAS = (float*)(pool + 141568);               // 128 B
  }

  __shared__ unsigned short s_ahi[240], s_alo[240];
  __shared__ unsigned short s_h0[1024];
  __shared__ float s_e[256];
  __shared__ float s_red[16];
  __shared__ float s_dp[128];
  __shared__ float s_ww[128];

  // ---- init: stage weights into LDS, zero state ----
  if (cu < 128){
    const unsigned short* src = A.W0p + (size_t)cu*48*2*512;
    for (int i = tid*8; i < 48*2*512; i += 2048)
      *(uint4*)(sW + i) = *(const uint4*)(src + i);
    if (cu >= 64 && cu < 75){
      const unsigned short* s2 = A.Woutp + (size_t)(cu-64)*40*512;
      for (int i = tid*8; i < 40*512; i += 2048)
        *(uint4*)(sWOUT + i) = *(const uint4*)(s2 + i);
    }
    if (tid < 32) sBIAS[tid] = A.b0p[cu*32 + tid];
  } else {
    const unsigned short* src = A.W1p + (size_t)(cu-128)*64*2*512;
    for (int i = tid*8; i < 64*2*512; i += 2048)
      *(uint4*)(sW + i) = *(const uint4*)(src + i);
    if (tid < 32) sBIAS[tid] = A.b1p[(cu-128)*32 + tid];
  }
  for (int i = tid; i < 512; i += 256) sCST[i] = 0.f;

  float accv = 0.f; int lenb = 0; float wwbv = 0.f;
  if (cu < 64) {
    lenb = A.tlen[cu];
    wwbv = A.wwb[0];
    float inv = 1.f / (float)lenb;
    for (int i = tid; i < 240; i += 256) {
      int t = i - 15;
      float v = (t >= 0 && t < 200 && t < lenb) ? inv : 0.f;
      unsigned short hi = f2b(v);
      s_ahi[i] = hi; s_alo[i] = f2b(v - b2f(hi));
    }
    if (tid < 200) accv = (tid < lenb) ? inv : 0.f;
    if (tid < 128) s_ww[tid] = A.ww[tid];
  }
  // (xh0/xh1/acbf zeroed by hipMemsetAsync on host — runtime dispatch
  //  acquire makes that visible)

  unsigned int ep = 0;
  gbar(A.bar, A.flag, ++ep, is_master);
  // one-time: drop any stale cached lines from previous graph replay
  __builtin_amdgcn_fence(__ATOMIC_ACQUIRE, "agent");

  for (int s = 0; s <= SS+1; ++s) {
    // ================= PHASE A =================
    if (cu < 64 && s < SS) {
      const int b = cu;
      const unsigned short* xh0r = A.xh0 + (size_t)((s+RING-1)&(RING-1))*65536;
      // ---- stage h0_{s-1}(b) into LDS ----
      if (tid < 128) *(uint4*)(s_h0 + tid*8) = *(const uint4*)(xh0r + b*1024 + tid*8);
      __syncthreads();
      // ---- dp[h] = h0 @ Wdec^T via MFMA (m=0 row only) ----
      {
        floatx4 acc0 = {0.f,0.f,0.f,0.f}, acc1 = {0.f,0.f,0.f,0.f};
        for (int ks=0; ks<32; ++ks){
          ABu av;
          if (ccol == 0) av.u4 = *(const uint4*)(s_h0 + ks*32 + q*8);
          else { av.u4.x=0; av.u4.y=0; av.u4.z=0; av.u4.w=0; }
          ABu bf0, bf1;
          bf0.u4 = *(const uint4*)(A.Wdecf + ((size_t)((w*2+0)*32+ks)*64 + L)*8);
          bf1.u4 = *(const uint4*)(A.Wdecf + ((size_t)((w*2+1)*32+ks)*64 + L)*8);
          acc0 = MFMA(av.v, bf0.v, acc0);
          acc1 = MFMA(av.v, bf1.v, acc1);
        }
        if (L < 16){
          s_dp[(w*2+0)*16 + ccol] = acc0[0];
          s_dp[(w*2+1)*16 + ccol] = acc1[0];
        }
      }
      __syncthreads();
      // ---- conv (MFMA, hi/lo split) + scores ----
      {
        ABu w2f[8];
        for (int nt=0; nt<8; ++nt) w2f[nt].u4 = *(const uint4*)(A.W2f + (nt*64 + L)*8);
        const unsigned short* pmrow = A.pmb + (size_t)b*200*128;
        for (int mt = w; mt < 13; mt += 4) {
          ABu ahi, alo;
          int abase = mt*16 + ccol + q*8;
          for (int j=0;j<8;++j){ ahi.us[j] = s_ahi[abase+j]; alo.us[j] = s_alo[abase+j]; }
          floatx4 acc[8];
          for (int nt=0;nt<8;++nt){
            floatx4 zz = {0.f,0.f,0.f,0.f};
            zz = MFMA(ahi.v, w2f[nt].v, zz);
            zz = MFMA(alo.v, w2f[nt].v, zz);
            acc[nt] = zz;
          }
          for (int r=0;r<4;++r){
            int t = mt*16 + q*4 + r;
            float part = 0.f;
            if (t < 200) {
              for (int nt=0;nt<8;++nt){
                int h = nt*16 + ccol;
                float v = acc[nt][r] + b2f(pmrow[t*128+h]) + s_dp[h];
                part += s_ww[h] * tanhf_fast(v);
              }
            }
            part += __shfl_xor(part, 1);
            part += __shfl_xor(part, 2);
            part += __shfl_xor(part, 4);
            part += __shfl_xor(part, 8);
            if (t < 200 && ccol == 0)
              s_e[t] = (t < lenb) ? (part + wwbv) : -1e30f;
          }
        }
      }
      __syncthreads();
      // ---- softmax (wave shuffles) + acc update ----
      {
        float v = (tid < 200) ? s_e[tid] : -1e30f;
        float m = v;
        for (int o=1;o<64;o<<=1) m = fmaxf(m, __shfl_xor(m, o));
        if (L == 0) s_red[w] = m;
        __syncthreads();
        m = fmaxf(fmaxf(s_red[0], s_red[1]), fmaxf(s_red[2], s_red[3]));
        float ex = (tid < 200) ? __expf(v - m) : 0.f;
        float sm = ex;
        for (int o=1;o<64;o<<=1) sm += __shfl_xor(sm, o);
        if (L == 0) s_red[8+w] = sm;
        __syncthreads();
        float inv = 1.f / (s_red[8]+s_red[9]+s_red[10]+s_red[11]);
        if (tid < 200){
          float aw = ex * inv;
          s_e[tid] = aw;
          A.dout[5184000 + (size_t)b*100000 + (size_t)s*200 + tid] = aw;
          accv = (s == 0) ? aw : (accv + aw);
          unsigned short hi = f2b(accv);
          s_ahi[15+tid] = hi; s_alo[15+tid] = f2b(accv - b2f(hi));
        }
      }
      __syncthreads();
      // ---- ac[c] = sum_t aw[t]*enc[b,t,c] ----
      {
        const unsigned short* er = A.encb + (size_t)b*200*256 + tid;
        float a0=0.f,a1=0.f,a2=0.f,a3=0.f;
        for (int t=0;t<200;t+=4){
          a0 += s_e[t  ]*b2f(er[(size_t)(t  )*256]);
          a1 += s_e[t+1]*b2f(er[(size_t)(t+1)*256]);
          a2 += s_e[t+2]*b2f(er[(size_t)(t+2)*256]);
          a3 += s_e[t+3]*b2f(er[(size_t)(t+3)*256]);
        }
        st_sc(A.acbf + (size_t)(s&(RING-1))*16384 + b*256 + tid, f2b((a0+a1)+(a2+a3)));
      }
    }
    if (cu >= 64 && cu < 75 && s >= 2) {
      // ---- output projection for step s-2 ----
      const int nt = cu - 64; const int s2 = s - 2;
      const unsigned short* segH  = A.xh1 + (size_t)(s2&(RING-1))*65536;
      const unsigned short* segAC = A.acbf + (size_t)(s2&(RING-1))*16384;
      floatx4 acc = {0.f,0.f,0.f,0.f};
      int brow = w*16 + ccol;
      for (int ks=0; ks<40; ++ks){
        const unsigned short* ap = (ks < 32) ? (segH + (size_t)brow*1024 + ks*32 + q*8)
                                             : (segAC + (size_t)brow*256 + (ks-32)*32 + q*8);
        ABu av; av.u4 = *(const uint4*)ap;
        ABu bf; bf.u4 = *(const uint4*)(sWOUT + ((size_t)ks*64 + L)*8);
        acc = MFMA(av.v, bf.v, acc);
      }
      int j = nt*16 + ccol;
      for (int r=0;r<4;++r){
        int b = w*16 + q*4 + r;
        float val = acc[r];
        if (j < 160){
          int rr = j/80, cc2 = j%80;
          A.dout[(size_t)b*80000 + (size_t)cc2*1000 + s2*2 + rr] = val;
        } else if (j < 162){
          A.dout[5120000 + (size_t)b*1000 + s2*2 + (j-160)] = val + A.probb[j-160];
        }
      }
    }
    if (cu >= 128 && s >= 1 && s <= SS) {
      // ---- LSTM1 for step s-1 ----
      const int cp = cu - 128;
      const unsigned short* segA = A.xh0 + (size_t)((s+RING-1)&(RING-1))*65536;
      const unsigned short* segB = A.xh1 + (size_t)((s+RING-2)&(RING-1))*65536;
      floatx4 a0 = {0.f,0.f,0.f,0.f}, a1 = {0.f,0.f,0.f,0.f};
      int brow = w*16 + ccol;
      for (int ks=0; ks<64; ++ks){
        const unsigned short* ap = (ks < 32) ? (segA + (size_t)brow*1024 + ks*32 + q*8)
                                             : (segB + (size_t)brow*1024 + (ks-32)*32 + q*8);
        ABu av; av.u4 = *(const uint4*)ap;
        ABu b0f, b1f;
        b0f.u4 = *(const uint4*)(sW + ((size_t)(ks*2+0)*64 + L)*8);
        b1f.u4 = *(const uint4*)(sW + ((size_t)(ks*2+1)*64 + L)*8);
        a0 = MFMA(av.v, b0f.v, a0);
        a1 = MFMA(av.v, b1f.v, a1);
      }
      for (int r=0;r<4;++r){
        int bb = w*16 + q*4 + r;
        sGB[bb*33 + ccol]      = a0[r] + sBIAS[ccol];
        sGB[bb*33 + 16 + ccol] = a1[r] + sBIAS[16+ccol];
      }
      __syncthreads();
      unsigned short* xout = A.xh1 + (size_t)((s+RING-1)&(RING-1))*65536;
      const unsigned short* hprev = segB;
      for (int rep=0;rep<2;++rep){
        int cell = tid + rep*256;
        int du = cell>>6, bb = cell&63;
        float gi=sGB[bb*33+du*4+0], gf=sGB[bb*33+du*4+1];
        float gg=sGB[bb*33+du*4+2], go=sGB[bb*33+du*4+3];
        float cprev = sCST[du*64+bb];
        float c2 = sigf(gf)*cprev + sigf(gi)*tanhf_fast(gg);
        float h2 = sigf(go)*tanhf_fast(c2);
        float cn = 0.1f*cprev + 0.9f*c2;
        float hp = b2f(hprev[(size_t)bb*1024 + cp*8 + du]);
        float hn = 0.1f*hp + 0.9f*h2;
        sCST[du*64+bb] = cn;
        st_sc(xout + (size_t)bb*1024 + cp*8 + du, f2b(hn));
      }
    }
    gbar(A.bar, A.flag, ++ep, is_master);
    // ================= PHASE B =================
    if (cu < 128 && s < SS) {
      // ---- LSTM0 for step s ----
      const unsigned short* segAC = A.acbf + (size_t)(s&(RING-1))*16384;
      const unsigned short* segP  = A.P + (size_t)s*64*256;
      const unsigned short* segH  = A.xh0 + (size_t)((s+RING-1)&(RING-1))*65536;
      floatx4 a0 = {0.f,0.f,0.f,0.f}, a1 = {0.f,0.f,0.f,0.f};
      int brow = w*16 + ccol;
      for (int ks=0; ks<48; ++ks){
        const unsigned short* ap;
        if (ks < 8)       ap = segAC + (size_t)brow*256  + ks*32 + q*8;
        else if (ks < 16) ap = segP  + (size_t)brow*256  + (ks-8)*32 + q*8;
        else              ap = segH  + (size_t)brow*1024 + (ks-16)*32 + q*8;
        ABu av; av.u4 = *(const uint4*)ap;
        ABu b0f, b1f;
        b0f.u4 = *(const uint4*)(sW + ((size_t)(ks*2+0)*64 + L)*8);
        b1f.u4 = *(const uint4*)(sW + ((size_t)(ks*2+1)*64 + L)*8);
        a0 = MFMA(av.v, b0f.v, a0);
        a1 = MFMA(av.v, b1f.v, a1);
      }
      for (int r=0;r<4;++r){
        int bb = w*16 + q*4 + r;
        sGB[bb*33 + ccol]      = a0[r] + sBIAS[ccol];
        sGB[bb*33 + 16 + ccol] = a1[r] + sBIAS[16+ccol];
      }
      __syncthreads();
      unsigned short* xout = A.xh0 + (size_t)(s&(RING-1))*65536;
      const unsigned short* hprev = segH;
      for (int rep=0;rep<2;++rep){
        int cell = tid + rep*256;
        int du = cell>>6, bb = cell&63;
        float gi=sGB[bb*33+du*4+0], gf=sGB[bb*33+du*4+1];
        float gg=sGB[bb*33+du*4+2], go=sGB[bb*33+du*4+3];
        float cprev = sCST[du*64+bb];
        float c2 = sigf(gf)*cprev + sigf(gi)*tanhf_fast(gg);
        float h2 = sigf(go)*tanhf_fast(c2);
        float cn = 0.1f*cprev + 0.9f*c2;
        float hp = b2f(hprev[(size_t)bb*1024 + cu*8 + du]);
        float hn = 0.1f*hp + 0.9f*h2;
        sCST[du*64+bb] = cn;
        st_sc(xout + (size_t)bb*1024 + cu*8 + du, f2b(hn));
      }
    }
    gbar(A.bar, A.flag, ++ep, is_master);
    // ---- ring hygiene: clear stale L1/L2 copies before slot reuse.
    // Smallest read->rewrite->read window is 13 iterations > 8, so one
    // acquire-inv every 8 iterations provably suffices (see analysis).
    if ((s & 7) == 4) __builtin_amdgcn_fence(__ATOMIC_ACQUIRE, "agent");
  }
}

// ---------------- host launcher ----------------

extern "C" void kernel_launch(void* const* d_in, const int* in_sizes, int n_in,
                              void* d_out, int out_size, void* d_ws, size_t ws_size,
                              hipStream_t stream)
{
  const float* enc   = (const float*)d_in[0];
  const int*   tlen  = (const int*)d_in[1];
  const float* ftgt  = (const float*)d_in[2];
  const float* aew   = (const float*)d_in[3];
  const float* aeb   = (const float*)d_in[4];
  const float* adw   = (const float*)d_in[5];
  const float* aaw   = (const float*)d_in[6];
  const float* acw   = (const float*)d_in[7];
  const float* aww   = (const float*)d_in[8];
  const float* awb   = (const float*)d_in[9];
  const float* pw0   = (const float*)d_in[10];
  const float* pb0   = (const float*)d_in[11];
  const float* pw1   = (const float*)d_in[12];
  const float* pb1   = (const float*)d_in[13];
  const float* l0wih = (const float*)d_in[14];
  const float* l0whh = (const float*)d_in[15];
  const float* l0bih = (const float*)d_in[16];
  const float* l0bhh = (const float*)d_in[17];
  const float* l1wih = (const float*)d_in[18];
  const float* l1whh = (const float*)d_in[19];
  const float* l1bih = (const float*)d_in[20];
  const float* l1bhh = (const float*)d_in[21];
  const float* fow   = (const float*)d_in[22];
  const float* pow_  = (const float*)d_in[23];
  const float* pob   = (const float*)d_in[24];
  float* dout = (float*)d_out;

  char* ws = (char*)d_ws;
  size_t off = 0;
  auto alloc = [&](size_t bytes)->void*{
    void* p = (void*)(ws + off);
    off += (bytes + 255) & ~(size_t)255;
    return p;
  };

  unsigned short* pmb   = (unsigned short*)alloc((size_t)64*200*128*2);
  unsigned short* encb  = (unsigned short*)alloc((size_t)64*200*256*2);
  unsigned short* W2f   = (unsigned short*)alloc((size_t)8*64*8*2);
  unsigned short* Wdecf = (unsigned short*)alloc((size_t)8*32*64*8*2);
  unsigned short* W0p   = (unsigned short*)alloc((size_t)128*48*2*512*2);
  unsigned short* W1p   = (unsigned short*)alloc((size_t)128*64*2*512*2);
  float* b0p            = (float*)alloc((size_t)4096*4);
  float* b1p            = (float*)alloc((size_t)4096*4);
  unsigned short* w0pp  = (unsigned short*)alloc((size_t)16*5*512*2);
  unsigned short* w1pp  = (unsigned short*)alloc((size_t)16*8*512*2);
  unsigned short* C1    = (unsigned short*)alloc((size_t)32000*256*2);
  unsigned short* P     = (unsigned short*)alloc((size_t)32000*256*2);
  unsigned short* Woutp = (unsigned short*)alloc((size_t)11*40*512*2);
  unsigned short* xh0   = (unsigned short*)alloc((size_t)RING*65536*2);
  unsigned short* xh1   = (unsigned short*)alloc((size_t)RING*65536*2);
  unsigned short* acbf  = (unsigned short*)alloc((size_t)RING*16384*2);
  unsigned int* bar     = (unsigned int*)alloc((size_t)NSLOT*128);
  unsigned int* flag    = (unsigned int*)alloc((size_t)NSLOT*128);

  hipMemsetAsync(bar, 0, (size_t)NSLOT*128, stream);
  hipMemsetAsync(flag, 0, (size_t)NSLOT*128, stream);
  hipMemsetAsync(xh0, 0, (size_t)RING*65536*2, stream);
  hipMemsetAsync(xh1, 0, (size_t)RING*65536*2, stream);
  hipMemsetAsync(acbf, 0, (size_t)RING*16384*2, stream);

  k_pm     <<<6400, 256, 0, stream>>>(enc, aew, aeb, pmb);
  k_encb   <<<12800,256, 0, stream>>>(enc, encb);
  k_w2f    <<<1,    256, 0, stream>>>(aaw, acw, W2f);
  k_packgen<<<64,   256, 0, stream>>>(adw, Wdecf, 128, 1024);
  k_packlstm<<<1536,256, 0, stream>>>(l0wih, l0whh, W0p, 512, 48);
  k_packlstm<<<2048,256, 0, stream>>>(l1wih, l1whh, W1p, 1024, 64);
  k_bias   <<<16,   256, 0, stream>>>(l0bih, l0bhh, l1bih, l1bhh, b0p, b1p);
  k_packgen<<<20,   256, 0, stream>>>(pw0, w0pp, 256, 160);
  k_packgen<<<32,   256, 0, stream>>>(pw1, w1pp, 256, 256);
  k_woutp  <<<110,  256, 0, stream>>>(fow, pow_, Woutp);
  k_pre1   <<<2000, 256, 0, stream>>>(ftgt, w0pp, pb0, C1);
  k_pre2   <<<2000, 256, 0, stream>>>(C1, w1pp, pb1, P);

  PArgs A;
  A.tlen = tlen; A.ww = aww; A.wwb = awb; A.probb = pob;
  A.pmb = pmb; A.encb = encb; A.W2f = W2f; A.Wdecf = Wdecf;
  A.W0p = W0p; A.W1p = W1p; A.b0p = b0p; A.b1p = b1p;
  A.P = P; A.Woutp = Woutp;
  A.xh0 = xh0; A.xh1 = xh1; A.acbf = acbf;
  A.bar = bar; A.flag = flag; A.dout = dout;

  hipFuncSetAttribute((const void*)k_decoder,
                      hipFuncAttributeMaxDynamicSharedMemorySize, DYN_LDS);
  k_decoder<<<NBLKS, 256, DYN_LDS, stream>>>(A);
}

// Round 3
// 18522.707 us; speedup vs baseline: 1.4313x; 1.1432x over previous
//
#include <hip/hip_runtime.h>

#define SS 500
#define NBLKS 256
#define NSLOT 64
#define DYN_LDS 157824
#define RING 32

typedef __bf16 bf16_t;
typedef bf16_t bf16x8 __attribute__((ext_vector_type(8)));
typedef float floatx4 __attribute__((ext_vector_type(4)));

union ABu { uint4 u4; bf16x8 v; unsigned short us[8]; };

#define MFMA(a,b,c) __builtin_amdgcn_mfma_f32_16x16x32_bf16((a),(b),(c),0,0,0)

__device__ __forceinline__ float b2f(unsigned short u){
  union { unsigned int ui; float f; } x; x.ui = ((unsigned int)u) << 16; return x.f;
}
__device__ __forceinline__ unsigned short f2b(float f){
  union { float f; unsigned int ui; } x; x.f = f;
  unsigned int r = x.ui + 0x7FFFu + ((x.ui >> 16) & 1u);
  return (unsigned short)(r >> 16);
}
__device__ __forceinline__ float sigf(float x){ return 1.f/(1.f + __expf(-x)); }
__device__ __forceinline__ float tanhf_fast(float x){
  x = fminf(fmaxf(x, -15.f), 15.f);
  float e = __expf(2.f*x);
  return (e - 1.f)/(e + 1.f);
}

// write-through store: lands at LLC (coherence point); enables fence-free barrier.
__device__ __forceinline__ void st_sc(unsigned short* p, unsigned short v){
  unsigned int w32 = v;
  asm volatile("global_store_short %0, %1, off sc0 sc1" :: "v"(p), "v"(w32) : "memory");
}

// async global->LDS DMA, 16B per lane, dest = wave-uniform base + lane*16
__device__ __forceinline__ void gld16(const void* g, void* l){
  __builtin_amdgcn_global_load_lds((const __attribute__((address_space(1))) unsigned int*)g,
                                   (__attribute__((address_space(3))) unsigned int*)l, 16, 0, 0);
}

#define WV(n) asm volatile("s_waitcnt vmcnt(" #n ")" ::: "memory")
__device__ __forceinline__ void wv_sel(int n){
  if (n >= 7) { WV(7); } else if (n == 6) { WV(6); } else if (n == 5) { WV(5); }
  else if (n == 4) { WV(4); } else if (n == 3) { WV(3); } else if (n == 2) { WV(2); }
  else if (n == 1) { WV(1); } else { WV(0); }
}

// ---- grid barrier: no agent fences. Cross-block data goes through sc0/sc1
// write-through stores; visibility needs only vmcnt(0) before arrival.
// Consumers use plain cached loads from ring-rotated buffers (RING=32);
// one acquire-inv every 16 steps clears stale copies before slot reuse.
__device__ __forceinline__ void gbar(unsigned int* slots, unsigned int* flag,
                                     unsigned int ep, int is_master){
  asm volatile("s_waitcnt vmcnt(0)" ::: "memory");
  __syncthreads();
  if (threadIdx.x == 0){
    __hip_atomic_fetch_add(&slots[(blockIdx.x & (NSLOT-1)) * 32], 1u,
                           __ATOMIC_RELAXED, __HIP_MEMORY_SCOPE_AGENT);
  }
  if (is_master){
    if (threadIdx.x < 64){
      for(;;){
        unsigned int v = __hip_atomic_load(&slots[threadIdx.x * 32],
                                           __ATOMIC_RELAXED, __HIP_MEMORY_SCOPE_AGENT);
        int t = (int)v;
        t += __shfl_xor(t, 1);  t += __shfl_xor(t, 2);  t += __shfl_xor(t, 4);
        t += __shfl_xor(t, 8);  t += __shfl_xor(t, 16); t += __shfl_xor(t, 32);
        if ((unsigned int)t >= ep * NBLKS) break;
        __builtin_amdgcn_s_sleep(1);
      }
      __hip_atomic_store(&flag[threadIdx.x * 32], ep,
                         __ATOMIC_RELAXED, __HIP_MEMORY_SCOPE_AGENT);
    }
  } else {
    if (threadIdx.x == 0){
      unsigned int* myf = &flag[(blockIdx.x & (NSLOT-1)) * 32];
      while (__hip_atomic_load(myf, __ATOMIC_RELAXED, __HIP_MEMORY_SCOPE_AGENT) < ep)
        __builtin_amdgcn_s_sleep(2);
    }
  }
  __syncthreads();
  asm volatile("" ::: "memory");
}

// ---------------- prep kernels ----------------

// processed memory, stored TRANSPOSED: pmT[b][h][t]
__global__ void k_pm(const float* __restrict__ enc, const float* __restrict__ ew,
                     const float* __restrict__ eb, unsigned short* __restrict__ pmT){
  int id = blockIdx.x*256 + threadIdx.x;
  if (id >= 64*200*128) return;
  int h = id & 127; int bt = id >> 7;
  const float* er = enc + (size_t)bt*256;
  const float* wr = ew + (size_t)h*256;
  float a0=eb[h], a1=0.f, a2=0.f, a3=0.f;
  for (int k=0;k<256;k+=4){
    a0 += er[k]*wr[k]; a1 += er[k+1]*wr[k+1]; a2 += er[k+2]*wr[k+2]; a3 += er[k+3]*wr[k+3];
  }
  int b = bt / 200, t = bt - b*200;
  pmT[(size_t)b*25600 + (size_t)h*200 + t] = f2b((a0+a1)+(a2+a3));
}

// encoder output, stored TRANSPOSED: encT[b][c][t] (vectorized ac-loop reads)
__global__ void k_encT(const float* __restrict__ enc, unsigned short* __restrict__ encT){
  int id = blockIdx.x*256 + threadIdx.x;
  if (id >= 64*256*200) return;
  int t = id % 200; int c = (id / 200) & 255; int b = id / 51200;
  encT[id] = f2b(enc[((size_t)b*200 + t)*256 + c]);
}

__global__ void k_w2f(const float* __restrict__ attw, const float* __restrict__ convw,
                      unsigned short* __restrict__ w2f){
  __shared__ float s_w2[128*31];
  int tid = threadIdx.x;
  for (int i = tid; i < 128*31; i += 256){
    int h = i / 31, k = i % 31;
    float v = 0.f;
    for (int c=0;c<32;++c) v += attw[h*32+c]*convw[c*31+k];
    s_w2[i] = v;
  }
  __syncthreads();
  for (int i = tid; i < 512; i += 256){
    int nt = i >> 6, lane = i & 63;
    int h = nt*16 + (lane&15);
    for (int j=0;j<8;++j){
      int k = (lane>>4)*8 + j;
      w2f[(nt*64+lane)*8+j] = f2b(k < 31 ? s_w2[h*31+k] : 0.f);
    }
  }
}

__global__ void k_packlstm(const float* __restrict__ wih, const float* __restrict__ whh,
                           unsigned short* __restrict__ dst, int Kih, int NKS){
  int id = blockIdx.x*256 + threadIdx.x;
  if (id >= 128*NKS*64) return;
  int lane = id & 63; int t = id >> 6; int cu = t / NKS;
  for (int nt=0; nt<2; ++nt){
    int n = nt*16 + (lane&15);
    int du = n>>2, g = n&3;
    int row = g*1024 + cu*8 + du;
    for (int j=0;j<8;++j){
      int k = (t % NKS)*32 + ((lane>>4)*8) + j;
      float v = (k < Kih) ? wih[(size_t)row*Kih + k] : whh[(size_t)row*1024 + (k - Kih)];
      dst[((size_t)(t*2+nt)*64 + lane)*8 + j] = f2b(v);
    }
  }
}

__global__ void k_bias(const float* bi0,const float* bh0,const float* bi1,const float* bh1,
                       float* b0p, float* b1p){
  int id = blockIdx.x*256 + threadIdx.x;
  if (id >= 4096) return;
  int cu = id>>5, n = id&31, du = n>>2, g = n&3;
  int row = g*1024 + cu*8 + du;
  b0p[id] = bi0[row] + bh0[row];
  b1p[id] = bi1[row] + bh1[row];
}

__global__ void k_packgen(const float* __restrict__ src, unsigned short* __restrict__ dst,
                          int N, int K){
  int tot = (N/16)*(K/32)*64;
  int id = blockIdx.x*256 + threadIdx.x;
  if (id >= tot) return;
  int lane = id & 63; int t = id >> 6;
  int nks = K/32;
  int n = (t / nks)*16 + (lane&15);
  for (int j=0;j<8;++j){
    int k = (t % nks)*32 + (lane>>4)*8 + j;
    dst[((size_t)t*64 + lane)*8 + j] = f2b(src[(size_t)n*K + k]);
  }
}

__global__ void k_woutp(const float* __restrict__ fw, const float* __restrict__ pw,
                        unsigned short* __restrict__ dst){
  int id = blockIdx.x*256 + threadIdx.x;
  if (id >= 11*40*64) return;
  int lane = id & 63; int t = id >> 6;
  int n = (t/40)*16 + (lane&15);
  for (int j=0;j<8;++j){
    int k = (t%40)*32 + (lane>>4)*8 + j;
    float v = 0.f;
    if (n < 160) v = fw[(size_t)n*1280 + k];
    else if (n < 162) v = pw[(size_t)(n-160)*1280 + k];
    dst[((size_t)t*64 + lane)*8 + j] = f2b(v);
  }
}

__global__ void k_pre1(const float* __restrict__ ftgt, const unsigned short* __restrict__ w0p,
                       const float* __restrict__ b0, unsigned short* __restrict__ C1){
  int mt = blockIdx.x;
  int tid = threadIdx.x, w = tid>>6, L = tid&63, ccol = L&15, q = L>>4;
  int sb0 = mt*16; int s = sb0 >> 6; int b0r = sb0 & 63;
  floatx4 z = {0.f,0.f,0.f,0.f};
  floatx4 acc[4] = {z,z,z,z};
  for (int ks=0; ks<5; ++ks){
    ABu av;
    if (s == 0){ av.u4.x=0; av.u4.y=0; av.u4.z=0; av.u4.w=0; }
    else {
      int b = b0r + ccol;
      for (int j=0;j<8;++j){
        int jj = ks*32 + q*8 + j;
        av.us[j] = f2b(ftgt[(size_t)b*80000 + (size_t)(jj%80)*1000 + (size_t)(s-1)*2 + (jj/80)]);
      }
    }
    for (int i=0;i<4;++i){
      ABu bf; bf.u4 = *(const uint4*)(w0p + ((size_t)((w*4+i)*5 + ks)*64 + L)*8);
      acc[i] = MFMA(av.v, bf.v, acc[i]);
    }
  }
  for (int i=0;i<4;++i){
    int icol = (w*4+i)*16 + ccol;
    float bia = b0[icol];
    for (int r=0;r<4;++r){
      int sb = sb0 + q*4 + r;
      C1[(size_t)sb*256 + icol] = f2b(fmaxf(acc[i][r] + bia, 0.f));
    }
  }
}

__global__ void k_pre2(const unsigned short* __restrict__ C1, const unsigned short* __restrict__ w1p,
                       const float* __restrict__ b1, unsigned short* __restrict__ P){
  int mt = blockIdx.x;
  int tid = threadIdx.x, w = tid>>6, L = tid&63, ccol = L&15, q = L>>4;
  int sb0 = mt*16;
  floatx4 z = {0.f,0.f,0.f,0.f};
  floatx4 acc[4] = {z,z,z,z};
  for (int ks=0; ks<8; ++ks){
    ABu av; av.u4 = *(const uint4*)(C1 + (size_t)(sb0+ccol)*256 + ks*32 + q*8);
    for (int i=0;i<4;++i){
      ABu bf; bf.u4 = *(const uint4*)(w1p + ((size_t)((w*4+i)*8 + ks)*64 + L)*8);
      acc[i] = MFMA(av.v, bf.v, acc[i]);
    }
  }
  for (int i=0;i<4;++i){
    int icol = (w*4+i)*16 + ccol;
    float bia = b1[icol];
    for (int r=0;r<4;++r){
      int sb = sb0 + q*4 + r;
      P[(size_t)sb*256 + icol] = f2b(fmaxf(acc[i][r] + bia, 0.f));
    }
  }
}

// ---------------- persistent decoder ----------------

struct PArgs {
  const int* tlen;
  const float* ww; const float* wwb; const float* probb;
  const unsigned short* pmT; const unsigned short* encT;
  const unsigned short* W2f; const unsigned short* Wdecf;
  const unsigned short* W0p; const unsigned short* W1p;
  const float* b0p; const float* b1p;
  const unsigned short* P; const unsigned short* Woutp;
  unsigned short* xh0; unsigned short* xh1; unsigned short* acbf;
  unsigned int* bar; unsigned int* flag;
  float* dout;
};

__global__ __launch_bounds__(256, 1) void k_decoder(PArgs A)
{
  const int cu = blockIdx.x;
  const int tid = threadIdx.x;
  const int w = tid>>6, L = tid&63;
  const int ccol = L&15, q = L>>4;
  const int is_master = (cu == NBLKS-1);

  extern __shared__ char pool[];
  unsigned short* sW;
  unsigned short* sRING;          // per-wave global_load_lds staging rings
  float* sGB; float* sCST; float* sBIAS;
  if (cu < 128){
    sW    = (unsigned short*)pool;                 // 98304  (LSTM0 weights)
    sRING = (unsigned short*)(pool + 98304);       // 32768  (8KB/wave)
    sGB   = (float*)(pool + 131072);               // 8448
    sCST  = (float*)(pool + 139520);               // 2048
    sBIAS = (float*)(pool + 141568);               // 128
  } else {
    sW    = (unsigned short*)pool;                 // 131072 (LSTM1 weights)
    sRING = (unsigned short*)(pool + 131072);      // 24576  (6KB/wave)
    sGB   = (float*)(pool + 131072);               // ALIAS of ring: only written after
                                                   // a block barrier that follows every
                                                   // wave's vmcnt(0) drain (see below)
    sCST  = (float*)(pool + 155648);               // 2048
    sBIAS = (float*)(pool + 157696);               // 128
  }

  __shared__ unsigned short s_ahi[240], s_alo[240];
  __shared__ unsigned short s_h0[1024];
  __shared__ float s_e[256];
  __shared__ float s_red[16];
  __shared__ float s_dp[128];
  __shared__ float s_ww[128];

  // ---- init: stage weights into LDS ----
  if (cu < 128){
    const unsigned short* src = A.W0p + (size_t)cu*48*2*512;
    for (int i = tid*8; i < 48*2*512; i += 2048)
      *(uint4*)(sW + i) = *(const uint4*)(src + i);
    if (tid < 32) sBIAS[tid] = A.b0p[cu*32 + tid];
  } else {
    const unsigned short* src = A.W1p + (size_t)(cu-128)*64*2*512;
    for (int i = tid*8; i < 64*2*512; i += 2048)
      *(uint4*)(sW + i) = *(const uint4*)(src + i);
    if (tid < 32) sBIAS[tid] = A.b1p[(cu-128)*32 + tid];
  }
  for (int i = tid; i < 512; i += 256) sCST[i] = 0.f;

  float accv = 0.f; int lenb = 0; float wwbv = 0.f;
  if (cu < 64) {
    lenb = A.tlen[cu];
    wwbv = A.wwb[0];
    float inv = 1.f / (float)lenb;
    for (int i = tid; i < 240; i += 256) {
      int t = i - 15;
      float v = (t >= 0 && t < 200 && t < lenb) ? inv : 0.f;
      unsigned short hi = f2b(v);
      s_ahi[i] = hi; s_alo[i] = f2b(v - b2f(hi));
    }
    if (tid < 200) accv = (tid < lenb) ? inv : 0.f;
    if (tid < 128) s_ww[tid] = A.ww[tid];
  }

  unsigned int ep = 0;
  gbar(A.bar, A.flag, ++ep, is_master);
  __builtin_amdgcn_fence(__ATOMIC_ACQUIRE, "agent");  // one-time clean slate

  for (int s = 0; s <= SS+1; ++s) {
    // ================= PHASE A =================
    if (cu < 64 && s < SS) {
      const int b = cu;
      const unsigned short* xh0r = A.xh0 + (size_t)((s+RING-1)&(RING-1))*65536;
      if (tid < 128) *(uint4*)(s_h0 + tid*8) = *(const uint4*)(xh0r + b*1024 + tid*8);
      __syncthreads();
      // ---- dp[h] = h0 @ Wdec^T : Wdecf staged via global_load_lds ring ----
      {
        unsigned short* ringw = sRING + w*4096;   // shorts (8KB/wave, 4 slots x 2KB)
        #pragma unroll
        for (int ks=0; ks<4; ++ks){
          gld16(A.Wdecf + ((size_t)((w*2+0)*32+ks)*512) + (size_t)L*8, ringw + ks*1024);
          gld16(A.Wdecf + ((size_t)((w*2+1)*32+ks)*512) + (size_t)L*8, ringw + ks*1024 + 512);
        }
        floatx4 acc0 = {0.f,0.f,0.f,0.f}, acc1 = {0.f,0.f,0.f,0.f};
        wv_sel(6);
        ABu av, bf0, bf1;
        if (ccol == 0) av.u4 = *(const uint4*)(s_h0 + q*8);
        else { av.u4.x=0; av.u4.y=0; av.u4.z=0; av.u4.w=0; }
        bf0.u4 = *(const uint4*)(ringw + L*8);
        bf1.u4 = *(const uint4*)(ringw + 512 + L*8);
        #pragma unroll
        for (int ks=0; ks<32; ++ks){
          if (ks+4 < 32){
            int k2 = ks+4;
            gld16(A.Wdecf + ((size_t)((w*2+0)*32+k2)*512) + (size_t)L*8, ringw + (k2&3)*1024);
            gld16(A.Wdecf + ((size_t)((w*2+1)*32+k2)*512) + (size_t)L*8, ringw + (k2&3)*1024 + 512);
          }
          ABu avn, c0, c1;
          if (ks+1 < 32){
            wv_sel(60-2*ks >= 6 ? 6 : 60-2*ks);
            if (ccol == 0) avn.u4 = *(const uint4*)(s_h0 + (ks+1)*32 + q*8);
            else { avn.u4.x=0; avn.u4.y=0; avn.u4.z=0; avn.u4.w=0; }
            c0.u4 = *(const uint4*)(ringw + ((ks+1)&3)*1024 + L*8);
            c1.u4 = *(const uint4*)(ringw + ((ks+1)&3)*1024 + 512 + L*8);
          } else { avn = av; c0 = bf0; c1 = bf1; }
          acc0 = MFMA(av.v, bf0.v, acc0);
          acc1 = MFMA(av.v, bf1.v, acc1);
          av = avn; bf0 = c0; bf1 = c1;
        }
        if (L < 16){
          s_dp[(w*2+0)*16 + ccol] = acc0[0];
          s_dp[(w*2+1)*16 + ccol] = acc1[0];
        }
      }
      __syncthreads();
      // ---- conv (MFMA, hi/lo split) + scores (pmT: 4-t vector loads) ----
      {
        ABu w2f[8];
        for (int nt=0; nt<8; ++nt) w2f[nt].u4 = *(const uint4*)(A.W2f + (nt*64 + L)*8);
        const unsigned short* pmrowT = A.pmT + (size_t)b*25600;
        for (int mt = w; mt < 13; mt += 4) {
          ABu ahi, alo;
          int abase = mt*16 + ccol + q*8;
          for (int j=0;j<8;++j){ ahi.us[j] = s_ahi[abase+j]; alo.us[j] = s_alo[abase+j]; }
          floatx4 acc[8];
          for (int nt=0;nt<8;++nt){
            floatx4 zz = {0.f,0.f,0.f,0.f};
            zz = MFMA(ahi.v, w2f[nt].v, zz);
            zz = MFMA(alo.v, w2f[nt].v, zz);
            acc[nt] = zz;
          }
          int t0 = mt*16 + q*4;
          union { ushort4 v; unsigned short us[4]; } pv[8];
          #pragma unroll
          for (int nt=0;nt<8;++nt)
            pv[nt].v = *(const ushort4*)(pmrowT + (size_t)(nt*16+ccol)*200 + t0);
          #pragma unroll
          for (int r=0;r<4;++r){
            int t = t0 + r;
            float part = 0.f;
            if (t < 200) {
              #pragma unroll
              for (int nt=0;nt<8;++nt){
                int h = nt*16 + ccol;
                float v = acc[nt][r] + b2f(pv[nt].us[r]) + s_dp[h];
                part += s_ww[h] * tanhf_fast(v);
              }
            }
            part += __shfl_xor(part, 1);
            part += __shfl_xor(part, 2);
            part += __shfl_xor(part, 4);
            part += __shfl_xor(part, 8);
            if (t < 200 && ccol == 0)
              s_e[t] = (t < lenb) ? (part + wwbv) : -1e30f;
          }
        }
      }
      __syncthreads();
      // ---- softmax + acc update ----
      {
        float v = (tid < 200) ? s_e[tid] : -1e30f;
        float m = v;
        for (int o=1;o<64;o<<=1) m = fmaxf(m, __shfl_xor(m, o));
        if (L == 0) s_red[w] = m;
        __syncthreads();
        m = fmaxf(fmaxf(s_red[0], s_red[1]), fmaxf(s_red[2], s_red[3]));
        float ex = (tid < 200) ? __expf(v - m) : 0.f;
        float sm = ex;
        for (int o=1;o<64;o<<=1) sm += __shfl_xor(sm, o);
        if (L == 0) s_red[8+w] = sm;
        __syncthreads();
        float inv = 1.f / (s_red[8]+s_red[9]+s_red[10]+s_red[11]);
        if (tid < 200){
          float aw = ex * inv;
          s_e[tid] = aw;
          A.dout[5184000 + (size_t)b*100000 + (size_t)s*200 + tid] = aw;
          accv = (s == 0) ? aw : (accv + aw);
          unsigned short hi = f2b(accv);
          s_ahi[15+tid] = hi; s_alo[15+tid] = f2b(accv - b2f(hi));
        }
      }
      __syncthreads();
      // ---- ac[c] = sum_t aw[t]*encT[b,c,t] (vectorized) ----
      {
        const unsigned short* er = A.encT + (size_t)b*51200 + (size_t)tid*200;
        float a0=0.f,a1=0.f,a2=0.f,a3=0.f;
        #pragma unroll 5
        for (int it=0; it<25; ++it){
          ABu v; v.u4 = *(const uint4*)(er + it*8);
          a0 += s_e[it*8+0]*b2f(v.us[0]); a1 += s_e[it*8+1]*b2f(v.us[1]);
          a2 += s_e[it*8+2]*b2f(v.us[2]); a3 += s_e[it*8+3]*b2f(v.us[3]);
          a0 += s_e[it*8+4]*b2f(v.us[4]); a1 += s_e[it*8+5]*b2f(v.us[5]);
          a2 += s_e[it*8+6]*b2f(v.us[6]); a3 += s_e[it*8+7]*b2f(v.us[7]);
        }
        st_sc(A.acbf + (size_t)(s&(RING-1))*16384 + b*256 + tid, f2b((a0+a1)+(a2+a3)));
      }
    }
    if (cu >= 75 && cu < 119 && s >= 2) {
      // ---- output projection for step s-2: 44 blocks = 11 n-tiles x 4 batch-groups,
      //      ks split across waves + LDS reduce (shrinks per-CU stream ~4x) ----
      const int oid = cu - 75; const int nt = oid % 11; const int mg = oid / 11;
      const int s2 = s - 2;
      const unsigned short* segH  = A.xh1 + (size_t)(s2&(RING-1))*65536;
      const unsigned short* segAC = A.acbf + (size_t)(s2&(RING-1))*16384;
      const unsigned short* wo = A.Woutp + (size_t)nt*40*512;
      floatx4 acc = {0.f,0.f,0.f,0.f};
      int brow = mg*16 + ccol;
      #pragma unroll
      for (int kk=0; kk<10; ++kk){
        int ks = w*10 + kk;
        const unsigned short* ap = (ks < 32) ? (segH + (size_t)brow*1024 + ks*32 + q*8)
                                             : (segAC + (size_t)brow*256 + (ks-32)*32 + q*8);
        ABu av; av.u4 = *(const uint4*)ap;
        ABu bf; bf.u4 = *(const uint4*)(wo + ((size_t)ks*64 + L)*8);
        acc = MFMA(av.v, bf.v, acc);
      }
      #pragma unroll
      for (int r=0;r<4;++r) sGB[w*256 + (q*4+r)*16 + ccol] = acc[r];
      __syncthreads();
      {
        float v = sGB[tid] + sGB[256+tid] + sGB[512+tid] + sGB[768+tid];
        int blocal = tid>>4, colp = tid&15;
        int j = nt*16 + colp; int bb = mg*16 + blocal;
        if (j < 160){
          int rr = j/80, cc2 = j%80;
          A.dout[(size_t)bb*80000 + (size_t)cc2*1000 + s2*2 + rr] = v;
        } else if (j < 162){
          A.dout[5120000 + (size_t)bb*1000 + s2*2 + (j-160)] = v + A.probb[j-160];
        }
      }
      __syncthreads();
    }
    if (cu >= 128 && s >= 1 && s <= SS) {
      // ---- LSTM1 for step s-1: A-operand staged via DMA ring (depth 6) ----
      const int cp = cu - 128;
      const unsigned short* segA = A.xh0 + (size_t)((s+RING-1)&(RING-1))*65536;
      const unsigned short* segB = A.xh1 + (size_t)((s+RING-2)&(RING-1))*65536;
      unsigned short* ringw = sRING + w*3072;
      const int srow = w*16 + (L>>2);
      const int koff = (L&3)*8;
      #pragma unroll
      for (int t=0;t<6;++t)
        gld16(segA + (size_t)srow*1024 + t*32 + koff, ringw + t*512);
      floatx4 a0 = {0.f,0.f,0.f,0.f}, a1 = {0.f,0.f,0.f,0.f};
      wv_sel(5);
      ABu av, b0f, b1f;
      av.u4  = *(const uint4*)(ringw + (ccol*4+q)*8);
      b0f.u4 = *(const uint4*)(sW + (size_t)(0*64 + L)*8);
      b1f.u4 = *(const uint4*)(sW + (size_t)(1*64 + L)*8);
      #pragma unroll
      for (int t=0;t<64;++t){
        if (t+6 < 64){
          int t2 = t+6;
          const unsigned short* sp = (t2 < 32) ? (segA + (size_t)srow*1024 + t2*32 + koff)
                                               : (segB + (size_t)srow*1024 + (t2-32)*32 + koff);
          gld16(sp, ringw + (t2%6)*512);
        }
        ABu avn, c0, c1;
        if (t+1 < 64){
          wv_sel(62-t >= 5 ? 5 : 62-t);
          avn.u4 = *(const uint4*)(ringw + ((t+1)%6)*512 + (ccol*4+q)*8);
          c0.u4 = *(const uint4*)(sW + ((size_t)((t+1)*2+0)*64 + L)*8);
          c1.u4 = *(const uint4*)(sW + ((size_t)((t+1)*2+1)*64 + L)*8);
        } else { avn = av; c0 = b0f; c1 = b1f; }
        a0 = MFMA(av.v, b0f.v, a0);
        a1 = MFMA(av.v, b1f.v, a1);
        av = avn; b0f = c0; b1f = c1;
      }
      // RACE FIX (v7): sGB aliases the DMA ring. Every wave has drained its
      // ring DMA (WV(0) at t=62) before arriving here, but a FAST wave's sGB
      // writes below would clobber a SLOW wave's ring slots mid-loop. Barrier
      // ensures all waves finished their MFMA loops before any sGB write.
      __syncthreads();
      #pragma unroll
      for (int r=0;r<4;++r){
        int bb = w*16 + q*4 + r;
        sGB[bb*33 + ccol]      = a0[r] + sBIAS[ccol];
        sGB[bb*33 + 16 + ccol] = a1[r] + sBIAS[16+ccol];
      }
      __syncthreads();
      unsigned short* xout = A.xh1 + (size_t)((s+RING-1)&(RING-1))*65536;
      const unsigned short* hprev = segB;
      for (int rep=0;rep<2;++rep){
        int cell = tid + rep*256;
        int du = cell>>6, bb = cell&63;
        float gi=sGB[bb*33+du*4+0], gf=sGB[bb*33+du*4+1];
        float gg=sGB[bb*33+du*4+2], go=sGB[bb*33+du*4+3];
        float cprev = sCST[du*64+bb];
        float c2 = sigf(gf)*cprev + sigf(gi)*tanhf_fast(gg);
        float h2 = sigf(go)*tanhf_fast(c2);
        float cn = 0.1f*cprev + 0.9f*c2;
        float hp = b2f(hprev[(size_t)bb*1024 + cp*8 + du]);
        float hn = 0.1f*hp + 0.9f*h2;
        sCST[du*64+bb] = cn;
        st_sc(xout + (size_t)bb*1024 + cp*8 + du, f2b(hn));
      }
    }
    gbar(A.bar, A.flag, ++ep, is_master);
    // ================= PHASE B =================
    if (cu < 128 && s < SS) {
      // ---- LSTM0 for step s: A-operand (ac|P|h0) staged via DMA ring (depth 8) ----
      const unsigned short* segAC = A.acbf + (size_t)(s&(RING-1))*16384;
      const unsigned short* segP  = A.P + (size_t)s*16384;
      const unsigned short* segH  = A.xh0 + (size_t)((s+RING-1)&(RING-1))*65536;
      unsigned short* ringw = sRING + w*4096;
      const int srow = w*16 + (L>>2);
      const int koff = (L&3)*8;
      #pragma unroll
      for (int t=0;t<8;++t)
        gld16(segAC + (size_t)srow*256 + t*32 + koff, ringw + t*512);
      floatx4 a0 = {0.f,0.f,0.f,0.f}, a1 = {0.f,0.f,0.f,0.f};
      wv_sel(7);
      ABu av, b0f, b1f;
      av.u4  = *(const uint4*)(ringw + (ccol*4+q)*8);
      b0f.u4 = *(const uint4*)(sW + (size_t)(0*64 + L)*8);
      b1f.u4 = *(const uint4*)(sW + (size_t)(1*64 + L)*8);
      #pragma unroll
      for (int t=0;t<48;++t){
        if (t+8 < 48){
          int t2 = t+8;
          const unsigned short* sp = (t2 < 16) ? (segP + (size_t)srow*256 + (t2-8)*32 + koff)
                                               : (segH + (size_t)srow*1024 + (t2-16)*32 + koff);
          gld16(sp, ringw + (t2&7)*512);
        }
        ABu avn, c0, c1;
        if (t+1 < 48){
          wv_sel(46-t >= 7 ? 7 : 46-t);
          avn.u4 = *(const uint4*)(ringw + ((t+1)&7)*512 + (ccol*4+q)*8);
          c0.u4 = *(const uint4*)(sW + ((size_t)((t+1)*2+0)*64 + L)*8);
          c1.u4 = *(const uint4*)(sW + ((size_t)((t+1)*2+1)*64 + L)*8);
        } else { avn = av; c0 = b0f; c1 = b1f; }
        a0 = MFMA(av.v, b0f.v, a0);
        a1 = MFMA(av.v, b1f.v, a1);
        av = avn; b0f = c0; b1f = c1;
      }
      // (no barrier needed here: for cu<128 sGB does NOT alias the ring)
      #pragma unroll
      for (int r=0;r<4;++r){
        int bb = w*16 + q*4 + r;
        sGB[bb*33 + ccol]      = a0[r] + sBIAS[ccol];
        sGB[bb*33 + 16 + ccol] = a1[r] + sBIAS[16+ccol];
      }
      __syncthreads();
      unsigned short* xout = A.xh0 + (size_t)(s&(RING-1))*65536;
      const unsigned short* hprev = segH;
      for (int rep=0;rep<2;++rep){
        int cell = tid + rep*256;
        int du = cell>>6, bb = cell&63;
        float gi=sGB[bb*33+du*4+0], gf=sGB[bb*33+du*4+1];
        float gg=sGB[bb*33+du*4+2], go=sGB[bb*33+du*4+3];
        float cprev = sCST[du*64+bb];
        float c2 = sigf(gf)*cprev + sigf(gi)*tanhf_fast(gg);
        float h2 = sigf(go)*tanhf_fast(c2);
        float cn = 0.1f*cprev + 0.9f*c2;
        float hp = b2f(hprev[(size_t)bb*1024 + cu*8 + du]);
        float hn = 0.1f*hp + 0.9f*h2;
        sCST[du*64+bb] = cn;
        st_sc(xout + (size_t)bb*1024 + cu*8 + du, f2b(hn));
      }
    }
    gbar(A.bar, A.flag, ++ep, is_master);
    // ring hygiene: RING=32 slots, max read lag 2 steps, rewrite at +32.
    // One acquire-inv per 16 steps guarantees an inv in every stale window.
    if ((s & 15) == 8) __builtin_amdgcn_fence(__ATOMIC_ACQUIRE, "agent");
  }
}

// ---------------- host launcher ----------------

extern "C" void kernel_launch(void* const* d_in, const int* in_sizes, int n_in,
                              void* d_out, int out_size, void* d_ws, size_t ws_size,
                              hipStream_t stream)
{
  const float* enc   = (const float*)d_in[0];
  const int*   tlen  = (const int*)d_in[1];
  const float* ftgt  = (const float*)d_in[2];
  const float* aew   = (const float*)d_in[3];
  const float* aeb   = (const float*)d_in[4];
  const float* adw   = (const float*)d_in[5];
  const float* aaw   = (const float*)d_in[6];
  const float* acw   = (const float*)d_in[7];
  const float* aww   = (const float*)d_in[8];
  const float* awb   = (const float*)d_in[9];
  const float* pw0   = (const float*)d_in[10];
  const float* pb0   = (const float*)d_in[11];
  const float* pw1   = (const float*)d_in[12];
  const float* pb1   = (const float*)d_in[13];
  const float* l0wih = (const float*)d_in[14];
  const float* l0whh = (const float*)d_in[15];
  const float* l0bih = (const float*)d_in[16];
  const float* l0bhh = (const float*)d_in[17];
  const float* l1wih = (const float*)d_in[18];
  const float* l1whh = (const float*)d_in[19];
  const float* l1bih = (const float*)d_in[20];
  const float* l1bhh = (const float*)d_in[21];
  const float* fow   = (const float*)d_in[22];
  const float* pow_  = (const float*)d_in[23];
  const float* pob   = (const float*)d_in[24];
  float* dout = (float*)d_out;

  char* ws = (char*)d_ws;
  size_t off = 0;
  auto alloc = [&](size_t bytes)->void*{
    void* p = (void*)(ws + off);
    off += (bytes + 255) & ~(size_t)255;
    return p;
  };

  unsigned short* pmT   = (unsigned short*)alloc((size_t)64*200*128*2 + 256);
  unsigned short* encT  = (unsigned short*)alloc((size_t)64*256*200*2);
  unsigned short* W2f   = (unsigned short*)alloc((size_t)8*64*8*2);
  unsigned short* Wdecf = (unsigned short*)alloc((size_t)8*32*64*8*2);
  unsigned short* W0p   = (unsigned short*)alloc((size_t)128*48*2*512*2);
  unsigned short* W1p   = (unsigned short*)alloc((size_t)128*64*2*512*2);
  float* b0p            = (float*)alloc((size_t)4096*4);
  float* b1p            = (float*)alloc((size_t)4096*4);
  unsigned short* w0pp  = (unsigned short*)alloc((size_t)16*5*512*2);
  unsigned short* w1pp  = (unsigned short*)alloc((size_t)16*8*512*2);
  unsigned short* C1    = (unsigned short*)alloc((size_t)32000*256*2);
  unsigned short* P     = (unsigned short*)alloc((size_t)32000*256*2);
  unsigned short* Woutp = (unsigned short*)alloc((size_t)11*40*512*2);
  unsigned short* xh0   = (unsigned short*)alloc((size_t)RING*65536*2);
  unsigned short* xh1   = (unsigned short*)alloc((size_t)RING*65536*2);
  unsigned short* acbf  = (unsigned short*)alloc((size_t)RING*16384*2);
  unsigned int* bar     = (unsigned int*)alloc((size_t)NSLOT*128);
  unsigned int* flag    = (unsigned int*)alloc((size_t)NSLOT*128);

  hipMemsetAsync(bar, 0, (size_t)NSLOT*128, stream);
  hipMemsetAsync(flag, 0, (size_t)NSLOT*128, stream);
  hipMemsetAsync(xh0, 0, (size_t)RING*65536*2, stream);
  hipMemsetAsync(xh1, 0, (size_t)RING*65536*2, stream);
  hipMemsetAsync(acbf, 0, (size_t)RING*16384*2, stream);

  k_pm     <<<6400, 256, 0, stream>>>(enc, aew, aeb, pmT);
  k_encT   <<<12800,256, 0, stream>>>(enc, encT);
  k_w2f    <<<1,    256, 0, stream>>>(aaw, acw, W2f);
  k_packgen<<<64,   256, 0, stream>>>(adw, Wdecf, 128, 1024);
  k_packlstm<<<1536,256, 0, stream>>>(l0wih, l0whh, W0p, 512, 48);
  k_packlstm<<<2048,256, 0, stream>>>(l1wih, l1whh, W1p, 1024, 64);
  k_bias   <<<16,   256, 0, stream>>>(l0bih, l0bhh, l1bih, l1bhh, b0p, b1p);
  k_packgen<<<20,   256, 0, stream>>>(pw0, w0pp, 256, 160);
  k_packgen<<<32,   256, 0, stream>>>(pw1, w1pp, 256, 256);
  k_woutp  <<<110,  256, 0, stream>>>(fow, pow_, Woutp);
  k_pre1   <<<2000, 256, 0, stream>>>(ftgt, w0pp, pb0, C1);
  k_pre2   <<<2000, 256, 0, stream>>>(C1, w1pp, pb1, P);

  PArgs A;
  A.tlen = tlen; A.ww = aww; A.wwb = awb; A.probb = pob;
  A.pmT = pmT; A.encT = encT; A.W2f = W2f; A.Wdecf = Wdecf;
  A.W0p = W0p; A.W1p = W1p; A.b0p = b0p; A.b1p = b1p;
  A.P = P; A.Woutp = Woutp;
  A.xh0 = xh0; A.xh1 = xh1; A.acbf = acbf;
  A.bar = bar; A.flag = flag; A.dout = dout;

  hipFuncSetAttribute((const void*)k_decoder,
                      hipFuncAttributeMaxDynamicSharedMemorySize, DYN_LDS);
  k_decoder<<<NBLKS, 256, DYN_LDS, stream>>>(A);
}

// Round 4
// 16906.198 us; speedup vs baseline: 1.5682x; 1.0956x over previous
//
#include <hip/hip_runtime.h>

#define SS 500
#define NBLKS 256
#define NSLOT 64
#define DYN_LDS 141824
#define RING 32

typedef __bf16 bf16_t;
typedef bf16_t bf16x8 __attribute__((ext_vector_type(8)));
typedef float floatx4 __attribute__((ext_vector_type(4)));

union ABu { uint4 u4; bf16x8 v; unsigned short us[8]; };

#define MFMA(a,b,c) __builtin_amdgcn_mfma_f32_16x16x32_bf16((a),(b),(c),0,0,0)

__device__ __forceinline__ float b2f(unsigned short u){
  union { unsigned int ui; float f; } x; x.ui = ((unsigned int)u) << 16; return x.f;
}
__device__ __forceinline__ unsigned short f2b(float f){
  union { float f; unsigned int ui; } x; x.f = f;
  unsigned int r = x.ui + 0x7FFFu + ((x.ui >> 16) & 1u);
  return (unsigned short)(r >> 16);
}
__device__ __forceinline__ float sigf(float x){ return 1.f/(1.f + __expf(-x)); }
__device__ __forceinline__ float tanhf_fast(float x){
  x = fminf(fmaxf(x, -15.f), 15.f);
  float e = __expf(2.f*x);
  return (e - 1.f)/(e + 1.f);
}

// write-through store: lands at LLC (coherence point); enables fence-free barrier.
__device__ __forceinline__ void st_sc(unsigned short* p, unsigned short v){
  unsigned int w32 = v;
  asm volatile("global_store_short %0, %1, off sc0 sc1" :: "v"(p), "v"(w32) : "memory");
}

// ---- grid barrier: no agent fences. Cross-block data goes through sc0/sc1
// write-through stores; visibility needs only vmcnt(0) before arrival.
// Consumers use plain cached loads from ring-rotated buffers (RING=32);
// one acquire-inv every 16 steps clears stale copies before slot reuse.
__device__ __forceinline__ void gbar(unsigned int* slots, unsigned int* flag,
                                     unsigned int ep, int is_master){
  asm volatile("s_waitcnt vmcnt(0)" ::: "memory");
  __syncthreads();
  if (threadIdx.x == 0){
    __hip_atomic_fetch_add(&slots[(blockIdx.x & (NSLOT-1)) * 32], 1u,
                           __ATOMIC_RELAXED, __HIP_MEMORY_SCOPE_AGENT);
  }
  if (is_master){
    if (threadIdx.x < 64){
      for(;;){
        unsigned int v = __hip_atomic_load(&slots[threadIdx.x * 32],
                                           __ATOMIC_RELAXED, __HIP_MEMORY_SCOPE_AGENT);
        int t = (int)v;
        t += __shfl_xor(t, 1);  t += __shfl_xor(t, 2);  t += __shfl_xor(t, 4);
        t += __shfl_xor(t, 8);  t += __shfl_xor(t, 16); t += __shfl_xor(t, 32);
        if ((unsigned int)t >= ep * NBLKS) break;
        __builtin_amdgcn_s_sleep(1);
      }
      __hip_atomic_store(&flag[threadIdx.x * 32], ep,
                         __ATOMIC_RELAXED, __HIP_MEMORY_SCOPE_AGENT);
    }
  } else {
    if (threadIdx.x == 0){
      unsigned int* myf = &flag[(blockIdx.x & (NSLOT-1)) * 32];
      while (__hip_atomic_load(myf, __ATOMIC_RELAXED, __HIP_MEMORY_SCOPE_AGENT) < ep)
        __builtin_amdgcn_s_sleep(2);
    }
  }
  __syncthreads();
  asm volatile("" ::: "memory");
}

// ---------------- prep kernels ----------------

// processed memory, stored TRANSPOSED: pmT[b][h][t]
__global__ void k_pm(const float* __restrict__ enc, const float* __restrict__ ew,
                     const float* __restrict__ eb, unsigned short* __restrict__ pmT){
  int id = blockIdx.x*256 + threadIdx.x;
  if (id >= 64*200*128) return;
  int h = id & 127; int bt = id >> 7;
  const float* er = enc + (size_t)bt*256;
  const float* wr = ew + (size_t)h*256;
  float a0=eb[h], a1=0.f, a2=0.f, a3=0.f;
  for (int k=0;k<256;k+=4){
    a0 += er[k]*wr[k]; a1 += er[k+1]*wr[k+1]; a2 += er[k+2]*wr[k+2]; a3 += er[k+3]*wr[k+3];
  }
  int b = bt / 200, t = bt - b*200;
  pmT[(size_t)b*25600 + (size_t)h*200 + t] = f2b((a0+a1)+(a2+a3));
}

// encoder output, stored TRANSPOSED: encT[b][c][t] (vectorized ac-loop reads)
__global__ void k_encT(const float* __restrict__ enc, unsigned short* __restrict__ encT){
  int id = blockIdx.x*256 + threadIdx.x;
  if (id >= 64*256*200) return;
  int t = id % 200; int c = (id / 200) & 255; int b = id / 51200;
  encT[id] = f2b(enc[((size_t)b*200 + t)*256 + c]);
}

__global__ void k_w2f(const float* __restrict__ attw, const float* __restrict__ convw,
                      unsigned short* __restrict__ w2f){
  __shared__ float s_w2[128*31];
  int tid = threadIdx.x;
  for (int i = tid; i < 128*31; i += 256){
    int h = i / 31, k = i % 31;
    float v = 0.f;
    for (int c=0;c<32;++c) v += attw[h*32+c]*convw[c*31+k];
    s_w2[i] = v;
  }
  __syncthreads();
  for (int i = tid; i < 512; i += 256){
    int nt = i >> 6, lane = i & 63;
    int h = nt*16 + (lane&15);
    for (int j=0;j<8;++j){
      int k = (lane>>4)*8 + j;
      w2f[(nt*64+lane)*8+j] = f2b(k < 31 ? s_w2[h*31+k] : 0.f);
    }
  }
}

__global__ void k_packlstm(const float* __restrict__ wih, const float* __restrict__ whh,
                           unsigned short* __restrict__ dst, int Kih, int NKS){
  int id = blockIdx.x*256 + threadIdx.x;
  if (id >= 128*NKS*64) return;
  int lane = id & 63; int t = id >> 6; int cu = t / NKS;
  for (int nt=0; nt<2; ++nt){
    int n = nt*16 + (lane&15);
    int du = n>>2, g = n&3;
    int row = g*1024 + cu*8 + du;
    for (int j=0;j<8;++j){
      int k = (t % NKS)*32 + ((lane>>4)*8) + j;
      float v = (k < Kih) ? wih[(size_t)row*Kih + k] : whh[(size_t)row*1024 + (k - Kih)];
      dst[((size_t)(t*2+nt)*64 + lane)*8 + j] = f2b(v);
    }
  }
}

__global__ void k_bias(const float* bi0,const float* bh0,const float* bi1,const float* bh1,
                       float* b0p, float* b1p){
  int id = blockIdx.x*256 + threadIdx.x;
  if (id >= 4096) return;
  int cu = id>>5, n = id&31, du = n>>2, g = n&3;
  int row = g*1024 + cu*8 + du;
  b0p[id] = bi0[row] + bh0[row];
  b1p[id] = bi1[row] + bh1[row];
}

__global__ void k_packgen(const float* __restrict__ src, unsigned short* __restrict__ dst,
                          int N, int K){
  int tot = (N/16)*(K/32)*64;
  int id = blockIdx.x*256 + threadIdx.x;
  if (id >= tot) return;
  int lane = id & 63; int t = id >> 6;
  int nks = K/32;
  int n = (t / nks)*16 + (lane&15);
  for (int j=0;j<8;++j){
    int k = (t % nks)*32 + (lane>>4)*8 + j;
    dst[((size_t)t*64 + lane)*8 + j] = f2b(src[(size_t)n*K + k]);
  }
}

__global__ void k_woutp(const float* __restrict__ fw, const float* __restrict__ pw,
                        unsigned short* __restrict__ dst){
  int id = blockIdx.x*256 + threadIdx.x;
  if (id >= 11*40*64) return;
  int lane = id & 63; int t = id >> 6;
  int n = (t/40)*16 + (lane&15);
  for (int j=0;j<8;++j){
    int k = (t%40)*32 + (lane>>4)*8 + j;
    float v = 0.f;
    if (n < 160) v = fw[(size_t)n*1280 + k];
    else if (n < 162) v = pw[(size_t)(n-160)*1280 + k];
    dst[((size_t)t*64 + lane)*8 + j] = f2b(v);
  }
}

__global__ void k_pre1(const float* __restrict__ ftgt, const unsigned short* __restrict__ w0p,
                       const float* __restrict__ b0, unsigned short* __restrict__ C1){
  int mt = blockIdx.x;
  int tid = threadIdx.x, w = tid>>6, L = tid&63, ccol = L&15, q = L>>4;
  int sb0 = mt*16; int s = sb0 >> 6; int b0r = sb0 & 63;
  floatx4 z = {0.f,0.f,0.f,0.f};
  floatx4 acc[4] = {z,z,z,z};
  for (int ks=0; ks<5; ++ks){
    ABu av;
    if (s == 0){ av.u4.x=0; av.u4.y=0; av.u4.z=0; av.u4.w=0; }
    else {
      int b = b0r + ccol;
      for (int j=0;j<8;++j){
        int jj = ks*32 + q*8 + j;
        av.us[j] = f2b(ftgt[(size_t)b*80000 + (size_t)(jj%80)*1000 + (size_t)(s-1)*2 + (jj/80)]);
      }
    }
    for (int i=0;i<4;++i){
      ABu bf; bf.u4 = *(const uint4*)(w0p + ((size_t)((w*4+i)*5 + ks)*64 + L)*8);
      acc[i] = MFMA(av.v, bf.v, acc[i]);
    }
  }
  for (int i=0;i<4;++i){
    int icol = (w*4+i)*16 + ccol;
    float bia = b0[icol];
    for (int r=0;r<4;++r){
      int sb = sb0 + q*4 + r;
      C1[(size_t)sb*256 + icol] = f2b(fmaxf(acc[i][r] + bia, 0.f));
    }
  }
}

__global__ void k_pre2(const unsigned short* __restrict__ C1, const unsigned short* __restrict__ w1p,
                       const float* __restrict__ b1, unsigned short* __restrict__ P){
  int mt = blockIdx.x;
  int tid = threadIdx.x, w = tid>>6, L = tid&63, ccol = L&15, q = L>>4;
  int sb0 = mt*16;
  floatx4 z = {0.f,0.f,0.f,0.f};
  floatx4 acc[4] = {z,z,z,z};
  for (int ks=0; ks<8; ++ks){
    ABu av; av.u4 = *(const uint4*)(C1 + (size_t)(sb0+ccol)*256 + ks*32 + q*8);
    for (int i=0;i<4;++i){
      ABu bf; bf.u4 = *(const uint4*)(w1p + ((size_t)((w*4+i)*8 + ks)*64 + L)*8);
      acc[i] = MFMA(av.v, bf.v, acc[i]);
    }
  }
  for (int i=0;i<4;++i){
    int icol = (w*4+i)*16 + ccol;
    float bia = b1[icol];
    for (int r=0;r<4;++r){
      int sb = sb0 + q*4 + r;
      P[(size_t)sb*256 + icol] = f2b(fmaxf(acc[i][r] + bia, 0.f));
    }
  }
}

// ---------------- persistent decoder ----------------

struct PArgs {
  const int* tlen;
  const float* ww; const float* wwb; const float* probb;
  const unsigned short* pmT; const unsigned short* encT;
  const unsigned short* W2f; const unsigned short* Wdecf;
  const unsigned short* W0p; const unsigned short* W1p;
  const float* b0p; const float* b1p;
  const unsigned short* P; const unsigned short* Woutp;
  unsigned short* xh0; unsigned short* xh1; unsigned short* acbf;
  unsigned int* bar; unsigned int* flag;
  float* dout;
};

__global__ __launch_bounds__(256, 1) void k_decoder(PArgs A)
{
  const int cu = blockIdx.x;
  const int tid = threadIdx.x;
  const int w = tid>>6, L = tid&63;
  const int ccol = L&15, q = L>>4;
  const int is_master = (cu == NBLKS-1);

  extern __shared__ char pool[];
  unsigned short* sW = (unsigned short*)pool;   // LSTM0: 98304 B / LSTM1: 131072 B
  float* sGB; float* sCST; float* sBIAS;
  if (cu < 128){
    sGB   = (float*)(pool + 98304);              // 8448 B (64*33 f32, padded)
    sCST  = (float*)(pool + 106752);             // 2048 B
    sBIAS = (float*)(pool + 108800);             // 128 B
  } else {
    sGB   = (float*)(pool + 131072);
    sCST  = (float*)(pool + 139520);
    sBIAS = (float*)(pool + 141568);
  }

  __shared__ unsigned short s_ahi[240], s_alo[240];
  __shared__ unsigned short s_h0[1024];
  __shared__ float s_e[256];
  __shared__ float s_red[16];
  __shared__ float s_dp[128];
  __shared__ float s_ww[128];

  // ---- init: stage weights into LDS ----
  if (cu < 128){
    const unsigned short* src = A.W0p + (size_t)cu*48*2*512;
    for (int i = tid*8; i < 48*2*512; i += 2048)
      *(uint4*)(sW + i) = *(const uint4*)(src + i);
    if (tid < 32) sBIAS[tid] = A.b0p[cu*32 + tid];
  } else {
    const unsigned short* src = A.W1p + (size_t)(cu-128)*64*2*512;
    for (int i = tid*8; i < 64*2*512; i += 2048)
      *(uint4*)(sW + i) = *(const uint4*)(src + i);
    if (tid < 32) sBIAS[tid] = A.b1p[(cu-128)*32 + tid];
  }
  for (int i = tid; i < 512; i += 256) sCST[i] = 0.f;

  float accv = 0.f; int lenb = 0; float wwbv = 0.f;
  ABu w2fr[8];   // conv weights, hoisted into registers for all 500 steps
  if (cu < 64) {
    lenb = A.tlen[cu];
    wwbv = A.wwb[0];
    float inv = 1.f / (float)lenb;
    for (int i = tid; i < 240; i += 256) {
      int t = i - 15;
      float v = (t >= 0 && t < 200 && t < lenb) ? inv : 0.f;
      unsigned short hi = f2b(v);
      s_ahi[i] = hi; s_alo[i] = f2b(v - b2f(hi));
    }
    if (tid < 200) accv = (tid < lenb) ? inv : 0.f;
    if (tid < 128) s_ww[tid] = A.ww[tid];
    #pragma unroll
    for (int nt=0; nt<8; ++nt) w2fr[nt].u4 = *(const uint4*)(A.W2f + (nt*64 + L)*8);
  }

  unsigned int ep = 0;
  gbar(A.bar, A.flag, ++ep, is_master);
  __builtin_amdgcn_fence(__ATOMIC_ACQUIRE, "agent");  // one-time clean slate

  for (int s = 0; s <= SS+1; ++s) {
    // ================= PHASE A =================
    if (cu < 64 && s < SS) {
      const int b = cu;
      const unsigned short* xh0r = A.xh0 + (size_t)((s+RING-1)&(RING-1))*65536;
      if (tid < 128) *(uint4*)(s_h0 + tid*8) = *(const uint4*)(xh0r + b*1024 + tid*8);
      __syncthreads();
      // ---- dp[h] = h0 @ Wdec^T : Wdecf reg-staged, prefetch depth 8 pairs ----
      {
        uint4 p0[8], p1[8];
        #pragma unroll
        for (int k=0;k<8;++k){
          p0[k] = *(const uint4*)(A.Wdecf + (size_t)((w*2+0)*32+k)*512 + (size_t)L*8);
          p1[k] = *(const uint4*)(A.Wdecf + (size_t)((w*2+1)*32+k)*512 + (size_t)L*8);
        }
        floatx4 acc0 = {0.f,0.f,0.f,0.f}, acc1 = {0.f,0.f,0.f,0.f};
        #pragma unroll
        for (int ks=0; ks<32; ++ks){
          ABu bf0, bf1; bf0.u4 = p0[ks&7]; bf1.u4 = p1[ks&7];
          if (ks+8 < 32){
            p0[ks&7] = *(const uint4*)(A.Wdecf + (size_t)((w*2+0)*32+ks+8)*512 + (size_t)L*8);
            p1[ks&7] = *(const uint4*)(A.Wdecf + (size_t)((w*2+1)*32+ks+8)*512 + (size_t)L*8);
          }
          ABu av;
          if (ccol == 0) av.u4 = *(const uint4*)(s_h0 + ks*32 + q*8);
          else { av.u4.x=0; av.u4.y=0; av.u4.z=0; av.u4.w=0; }
          acc0 = MFMA(av.v, bf0.v, acc0);
          acc1 = MFMA(av.v, bf1.v, acc1);
        }
        if (L < 16){
          s_dp[(w*2+0)*16 + ccol] = acc0[0];
          s_dp[(w*2+1)*16 + ccol] = acc1[0];
        }
      }
      __syncthreads();
      // ---- conv (MFMA, hi/lo split) + scores (pmT: 4-t vector loads) ----
      {
        const unsigned short* pmrowT = A.pmT + (size_t)b*25600;
        for (int mt = w; mt < 13; mt += 4) {
          ABu ahi, alo;
          int abase = mt*16 + ccol + q*8;
          for (int j=0;j<8;++j){ ahi.us[j] = s_ahi[abase+j]; alo.us[j] = s_alo[abase+j]; }
          floatx4 acc[8];
          for (int nt=0;nt<8;++nt){
            floatx4 zz = {0.f,0.f,0.f,0.f};
            zz = MFMA(ahi.v, w2fr[nt].v, zz);
            zz = MFMA(alo.v, w2fr[nt].v, zz);
            acc[nt] = zz;
          }
          int t0 = mt*16 + q*4;
          union { ushort4 v; unsigned short us[4]; } pv[8];
          #pragma unroll
          for (int nt=0;nt<8;++nt)
            pv[nt].v = *(const ushort4*)(pmrowT + (size_t)(nt*16+ccol)*200 + t0);
          #pragma unroll
          for (int r=0;r<4;++r){
            int t = t0 + r;
            float part = 0.f;
            if (t < 200) {
              #pragma unroll
              for (int nt=0;nt<8;++nt){
                int h = nt*16 + ccol;
                float v = acc[nt][r] + b2f(pv[nt].us[r]) + s_dp[h];
                part += s_ww[h] * tanhf_fast(v);
              }
            }
            part += __shfl_xor(part, 1);
            part += __shfl_xor(part, 2);
            part += __shfl_xor(part, 4);
            part += __shfl_xor(part, 8);
            if (t < 200 && ccol == 0)
              s_e[t] = (t < lenb) ? (part + wwbv) : -1e30f;
          }
        }
      }
      __syncthreads();
      // ---- softmax + acc update ----
      {
        float v = (tid < 200) ? s_e[tid] : -1e30f;
        float m = v;
        for (int o=1;o<64;o<<=1) m = fmaxf(m, __shfl_xor(m, o));
        if (L == 0) s_red[w] = m;
        __syncthreads();
        m = fmaxf(fmaxf(s_red[0], s_red[1]), fmaxf(s_red[2], s_red[3]));
        float ex = (tid < 200) ? __expf(v - m) : 0.f;
        float sm = ex;
        for (int o=1;o<64;o<<=1) sm += __shfl_xor(sm, o);
        if (L == 0) s_red[8+w] = sm;
        __syncthreads();
        float inv = 1.f / (s_red[8]+s_red[9]+s_red[10]+s_red[11]);
        if (tid < 200){
          float aw = ex * inv;
          s_e[tid] = aw;
          A.dout[5184000 + (size_t)b*100000 + (size_t)s*200 + tid] = aw;
          accv = (s == 0) ? aw : (accv + aw);
          unsigned short hi = f2b(accv);
          s_ahi[15+tid] = hi; s_alo[15+tid] = f2b(accv - b2f(hi));
        }
      }
      __syncthreads();
      // ---- ac[c] = sum_t aw[t]*encT[b,c,t] (vectorized) ----
      {
        const unsigned short* er = A.encT + (size_t)b*51200 + (size_t)tid*200;
        float a0=0.f,a1=0.f,a2=0.f,a3=0.f;
        #pragma unroll 5
        for (int it=0; it<25; ++it){
          ABu v; v.u4 = *(const uint4*)(er + it*8);
          a0 += s_e[it*8+0]*b2f(v.us[0]); a1 += s_e[it*8+1]*b2f(v.us[1]);
          a2 += s_e[it*8+2]*b2f(v.us[2]); a3 += s_e[it*8+3]*b2f(v.us[3]);
          a0 += s_e[it*8+4]*b2f(v.us[4]); a1 += s_e[it*8+5]*b2f(v.us[5]);
          a2 += s_e[it*8+6]*b2f(v.us[6]); a3 += s_e[it*8+7]*b2f(v.us[7]);
        }
        st_sc(A.acbf + (size_t)(s&(RING-1))*16384 + b*256 + tid, f2b((a0+a1)+(a2+a3)));
      }
    }
    if (cu >= 75 && cu < 119 && s >= 2) {
      // ---- output projection for step s-2: all 10 A-frags + 10 W-frags issued
      //      upfront (reg-staged), then MFMA chain; LDS reduce across waves ----
      const int nt = (cu-75) % 11; const int mg = (cu-75) / 11;
      const int s2 = s - 2;
      const unsigned short* segH  = A.xh1 + (size_t)(s2&(RING-1))*65536;
      const unsigned short* segAC = A.acbf + (size_t)(s2&(RING-1))*16384;
      const unsigned short* wo = A.Woutp + (size_t)nt*40*512;
      const int brow = mg*16 + ccol;
      uint4 ap[10], wp[10];
      #pragma unroll
      for (int kk=0; kk<10; ++kk){
        int ks = w*10 + kk;
        ap[kk] = *(const uint4*)((ks < 32) ? (segH + (size_t)brow*1024 + ks*32 + q*8)
                                           : (segAC + (size_t)brow*256 + (ks-32)*32 + q*8));
        wp[kk] = *(const uint4*)(wo + (size_t)ks*512 + (size_t)L*8);
      }
      floatx4 acc = {0.f,0.f,0.f,0.f};
      #pragma unroll
      for (int kk=0; kk<10; ++kk){
        ABu av, bf; av.u4 = ap[kk]; bf.u4 = wp[kk];
        acc = MFMA(av.v, bf.v, acc);
      }
      #pragma unroll
      for (int r=0;r<4;++r) sGB[w*256 + (q*4+r)*16 + ccol] = acc[r];
      __syncthreads();
      {
        float v = sGB[tid] + sGB[256+tid] + sGB[512+tid] + sGB[768+tid];
        int blocal = tid>>4, colp = tid&15;
        int j = nt*16 + colp; int bb = mg*16 + blocal;
        if (j < 160){
          int rr = j/80, cc2 = j%80;
          A.dout[(size_t)bb*80000 + (size_t)cc2*1000 + s2*2 + rr] = v;
        } else if (j < 162){
          A.dout[5120000 + (size_t)bb*1000 + s2*2 + (j-160)] = v + A.probb[j-160];
        }
      }
      __syncthreads();
    }
    if (cu >= 128 && s >= 1 && s <= SS) {
      // ---- LSTM1 for step s-1: A-operand reg-staged, prefetch depth 16 ----
      const int cp = cu - 128;
      const unsigned short* segA = A.xh0 + (size_t)((s+RING-1)&(RING-1))*65536;
      const unsigned short* segB = A.xh1 + (size_t)((s+RING-2)&(RING-1))*65536;
      const int brow = w*16 + ccol;
      uint4 pp[16];
      #pragma unroll
      for (int t=0;t<16;++t)
        pp[t] = *(const uint4*)(segA + (size_t)brow*1024 + t*32 + q*8);
      floatx4 a0 = {0.f,0.f,0.f,0.f}, a1 = {0.f,0.f,0.f,0.f};
      #pragma unroll
      for (int t=0;t<64;++t){
        ABu av; av.u4 = pp[t&15];
        ABu b0f, b1f;
        b0f.u4 = *(const uint4*)(sW + (size_t)(t*2+0)*512 + L*8);
        b1f.u4 = *(const uint4*)(sW + (size_t)(t*2+1)*512 + L*8);
        if (t+16 < 64){
          int t2 = t+16;
          const unsigned short* sp = (t2 < 32) ? (segA + (size_t)brow*1024 + t2*32 + q*8)
                                               : (segB + (size_t)brow*1024 + (t2-32)*32 + q*8);
          pp[t&15] = *(const uint4*)sp;
        }
        a0 = MFMA(av.v, b0f.v, a0);
        a1 = MFMA(av.v, b1f.v, a1);
      }
      #pragma unroll
      for (int r=0;r<4;++r){
        int bb = w*16 + q*4 + r;
        sGB[bb*33 + ccol]      = a0[r] + sBIAS[ccol];
        sGB[bb*33 + 16 + ccol] = a1[r] + sBIAS[16+ccol];
      }
      __syncthreads();
      unsigned short* xout = A.xh1 + (size_t)((s+RING-1)&(RING-1))*65536;
      const unsigned short* hprev = segB;
      for (int rep=0;rep<2;++rep){
        int cell = tid + rep*256;
        int du = cell>>6, bb = cell&63;
        float gi=sGB[bb*33+du*4+0], gf=sGB[bb*33+du*4+1];
        float gg=sGB[bb*33+du*4+2], go=sGB[bb*33+du*4+3];
        float cprev = sCST[du*64+bb];
        float c2 = sigf(gf)*cprev + sigf(gi)*tanhf_fast(gg);
        float h2 = sigf(go)*tanhf_fast(c2);
        float cn = 0.1f*cprev + 0.9f*c2;
        float hp = b2f(hprev[(size_t)bb*1024 + cp*8 + du]);
        float hn = 0.1f*hp + 0.9f*h2;
        sCST[du*64+bb] = cn;
        st_sc(xout + (size_t)bb*1024 + cp*8 + du, f2b(hn));
      }
    }
    // ---- LSTM0 prologue: K reordered to (P, h0, acbf-last) so the first 16
    //      fragments don't depend on this step's attention output; issue their
    //      loads BEFORE the barrier — the barrier's vmcnt(0) wait absorbs the
    //      latency for free. ----
    uint4 pre[16];
    const unsigned short *l0P = nullptr, *l0H = nullptr, *l0AC = nullptr;
    if (cu < 128 && s < SS){
      l0AC = A.acbf + (size_t)(s&(RING-1))*16384;
      l0P  = A.P + (size_t)s*16384;
      l0H  = A.xh0 + (size_t)((s+RING-1)&(RING-1))*65536;
      const int brow = w*16 + ccol;
      #pragma unroll
      for (int t=0;t<8;++t)
        pre[t]   = *(const uint4*)(l0P + (size_t)brow*256 + t*32 + q*8);
      #pragma unroll
      for (int t=0;t<8;++t)
        pre[8+t] = *(const uint4*)(l0H + (size_t)brow*1024 + t*32 + q*8);
    }
    gbar(A.bar, A.flag, ++ep, is_master);
    // ================= PHASE B =================
    if (cu < 128 && s < SS) {
      // ---- LSTM0 for step s: reg-staged, depth 16; K-order P(8),h0(32),ac(8) ----
      const int brow = w*16 + ccol;
      floatx4 a0 = {0.f,0.f,0.f,0.f}, a1 = {0.f,0.f,0.f,0.f};
      #pragma unroll
      for (int t=0;t<48;++t){
        ABu av; av.u4 = pre[t&15];
        // weight slot in original packing order: acbf=0-7, P=8-15, h0=16-47
        int ow = (t < 8) ? (8+t) : ((t < 40) ? (16+(t-8)) : (t-40));
        ABu b0f, b1f;
        b0f.u4 = *(const uint4*)(sW + (size_t)(ow*2+0)*512 + L*8);
        b1f.u4 = *(const uint4*)(sW + (size_t)(ow*2+1)*512 + L*8);
        if (t+16 < 48){
          int t2 = t+16;
          const unsigned short* sp = (t2 < 40) ? (l0H + (size_t)brow*1024 + (t2-8)*32 + q*8)
                                               : (l0AC + (size_t)brow*256 + (t2-40)*32 + q*8);
          pre[t&15] = *(const uint4*)sp;
        }
        a0 = MFMA(av.v, b0f.v, a0);
        a1 = MFMA(av.v, b1f.v, a1);
      }
      #pragma unroll
      for (int r=0;r<4;++r){
        int bb = w*16 + q*4 + r;
        sGB[bb*33 + ccol]      = a0[r] + sBIAS[ccol];
        sGB[bb*33 + 16 + ccol] = a1[r] + sBIAS[16+ccol];
      }
      __syncthreads();
      unsigned short* xout = A.xh0 + (size_t)(s&(RING-1))*65536;
      const unsigned short* hprev = l0H;
      for (int rep=0;rep<2;++rep){
        int cell = tid + rep*256;
        int du = cell>>6, bb = cell&63;
        float gi=sGB[bb*33+du*4+0], gf=sGB[bb*33+du*4+1];
        float gg=sGB[bb*33+du*4+2], go=sGB[bb*33+du*4+3];
        float cprev = sCST[du*64+bb];
        float c2 = sigf(gf)*cprev + sigf(gi)*tanhf_fast(gg);
        float h2 = sigf(go)*tanhf_fast(c2);
        float cn = 0.1f*cprev + 0.9f*c2;
        float hp = b2f(hprev[(size_t)bb*1024 + cu*8 + du]);
        float hn = 0.1f*hp + 0.9f*h2;
        sCST[du*64+bb] = cn;
        st_sc(xout + (size_t)bb*1024 + cu*8 + du, f2b(hn));
      }
    }
    gbar(A.bar, A.flag, ++ep, is_master);
    // ring hygiene: RING=32 slots, max read lag 2 steps, rewrite at +32.
    // One acquire-inv per 16 steps guarantees an inv in every stale window.
    if ((s & 15) == 8) __builtin_amdgcn_fence(__ATOMIC_ACQUIRE, "agent");
  }
}

// ---------------- host launcher ----------------

extern "C" void kernel_launch(void* const* d_in, const int* in_sizes, int n_in,
                              void* d_out, int out_size, void* d_ws, size_t ws_size,
                              hipStream_t stream)
{
  const float* enc   = (const float*)d_in[0];
  const int*   tlen  = (const int*)d_in[1];
  const float* ftgt  = (const float*)d_in[2];
  const float* aew   = (const float*)d_in[3];
  const float* aeb   = (const float*)d_in[4];
  const float* adw   = (const float*)d_in[5];
  const float* aaw   = (const float*)d_in[6];
  const float* acw   = (const float*)d_in[7];
  const float* aww   = (const float*)d_in[8];
  const float* awb   = (const float*)d_in[9];
  const float* pw0   = (const float*)d_in[10];
  const float* pb0   = (const float*)d_in[11];
  const float* pw1   = (const float*)d_in[12];
  const float* pb1   = (const float*)d_in[13];
  const float* l0wih = (const float*)d_in[14];
  const float* l0whh = (const float*)d_in[15];
  const float* l0bih = (const float*)d_in[16];
  const float* l0bhh = (const float*)d_in[17];
  const float* l1wih = (const float*)d_in[18];
  const float* l1whh = (const float*)d_in[19];
  const float* l1bih = (const float*)d_in[20];
  const float* l1bhh = (const float*)d_in[21];
  const float* fow   = (const float*)d_in[22];
  const float* pow_  = (const float*)d_in[23];
  const float* pob   = (const float*)d_in[24];
  float* dout = (float*)d_out;

  char* ws = (char*)d_ws;
  size_t off = 0;
  auto alloc = [&](size_t bytes)->void*{
    void* p = (void*)(ws + off);
    off += (bytes + 255) & ~(size_t)255;
    return p;
  };

  unsigned short* pmT   = (unsigned short*)alloc((size_t)64*200*128*2 + 256);
  unsigned short* encT  = (unsigned short*)alloc((size_t)64*256*200*2);
  unsigned short* W2f   = (unsigned short*)alloc((size_t)8*64*8*2);
  unsigned short* Wdecf = (unsigned short*)alloc((size_t)8*32*64*8*2);
  unsigned short* W0p   = (unsigned short*)alloc((size_t)128*48*2*512*2);
  unsigned short* W1p   = (unsigned short*)alloc((size_t)128*64*2*512*2);
  float* b0p            = (float*)alloc((size_t)4096*4);
  float* b1p            = (float*)alloc((size_t)4096*4);
  unsigned short* w0pp  = (unsigned short*)alloc((size_t)16*5*512*2);
  unsigned short* w1pp  = (unsigned short*)alloc((size_t)16*8*512*2);
  unsigned short* C1    = (unsigned short*)alloc((size_t)32000*256*2);
  unsigned short* P     = (unsigned short*)alloc((size_t)32000*256*2);
  unsigned short* Woutp = (unsigned short*)alloc((size_t)11*40*512*2);
  unsigned short* xh0   = (unsigned short*)alloc((size_t)RING*65536*2);
  unsigned short* xh1   = (unsigned short*)alloc((size_t)RING*65536*2);
  unsigned short* acbf  = (unsigned short*)alloc((size_t)RING*16384*2);
  unsigned int* bar     = (unsigned int*)alloc((size_t)NSLOT*128);
  unsigned int* flag    = (unsigned int*)alloc((size_t)NSLOT*128);

  hipMemsetAsync(bar, 0, (size_t)NSLOT*128, stream);
  hipMemsetAsync(flag, 0, (size_t)NSLOT*128, stream);
  hipMemsetAsync(xh0, 0, (size_t)RING*65536*2, stream);
  hipMemsetAsync(xh1, 0, (size_t)RING*65536*2, stream);
  hipMemsetAsync(acbf, 0, (size_t)RING*16384*2, stream);

  k_pm     <<<6400, 256, 0, stream>>>(enc, aew, aeb, pmT);
  k_encT   <<<12800,256, 0, stream>>>(enc, encT);
  k_w2f    <<<1,    256, 0, stream>>>(aaw, acw, W2f);
  k_packgen<<<64,   256, 0, stream>>>(adw, Wdecf, 128, 1024);
  k_packlstm<<<1536,256, 0, stream>>>(l0wih, l0whh, W0p, 512, 48);
  k_packlstm<<<2048,256, 0, stream>>>(l1wih, l1whh, W1p, 1024, 64);
  k_bias   <<<16,   256, 0, stream>>>(l0bih, l0bhh, l1bih, l1bhh, b0p, b1p);
  k_packgen<<<20,   256, 0, stream>>>(pw0, w0pp, 256, 160);
  k_packgen<<<32,   256, 0, stream>>>(pw1, w1pp, 256, 256);
  k_woutp  <<<110,  256, 0, stream>>>(fow, pow_, Woutp);
  k_pre1   <<<2000, 256, 0, stream>>>(ftgt, w0pp, pb0, C1);
  k_pre2   <<<2000, 256, 0, stream>>>(C1, w1pp, pb1, P);

  PArgs A;
  A.tlen = tlen; A.ww = aww; A.wwb = awb; A.probb = pob;
  A.pmT = pmT; A.encT = encT; A.W2f = W2f; A.Wdecf = Wdecf;
  A.W0p = W0p; A.W1p = W1p; A.b0p = b0p; A.b1p = b1p;
  A.P = P; A.Woutp = Woutp;
  A.xh0 = xh0; A.xh1 = xh1; A.acbf = acbf;
  A.bar = bar; A.flag = flag; A.dout = dout;

  hipFuncSetAttribute((const void*)k_decoder,
                      hipFuncAttributeMaxDynamicSharedMemorySize, DYN_LDS);
  k_decoder<<<NBLKS, 256, DYN_LDS, stream>>>(A);
}

// Round 5
// 14530.627 us; speedup vs baseline: 1.8245x; 1.1635x over previous
//
#include <hip/hip_runtime.h>

#define SS 500
#define NBLKS 256
#define NSLOT 64
#define DYN_LDS 152064
#define RING 32

typedef __bf16 bf16_t;
typedef bf16_t bf16x8 __attribute__((ext_vector_type(8)));
typedef float floatx4 __attribute__((ext_vector_type(4)));

union ABu { uint4 u4; bf16x8 v; unsigned short us[8]; };
union USu { ushort4 v; unsigned short us[4]; };

#define MFMA(a,b,c) __builtin_amdgcn_mfma_f32_16x16x32_bf16((a),(b),(c),0,0,0)

__device__ __forceinline__ float b2f(unsigned short u){
  union { unsigned int ui; float f; } x; x.ui = ((unsigned int)u) << 16; return x.f;
}
__device__ __forceinline__ unsigned short f2b(float f){
  union { float f; unsigned int ui; } x; x.f = f;
  unsigned int r = x.ui + 0x7FFFu + ((x.ui >> 16) & 1u);
  return (unsigned short)(r >> 16);
}
__device__ __forceinline__ float sigf(float x){ return 1.f/(1.f + __expf(-x)); }
__device__ __forceinline__ float tanhf_fast(float x){
  x = fminf(fmaxf(x, -15.f), 15.f);
  float e = __expf(2.f*x);
  return (e - 1.f)/(e + 1.f);
}

// write-through stores: land at LLC (coherence point); enable fence-free barrier.
__device__ __forceinline__ void st_sc(unsigned short* p, unsigned short v){
  unsigned int w32 = v;
  asm volatile("global_store_short %0, %1, off sc0 sc1" :: "v"(p), "v"(w32) : "memory");
}
__device__ __forceinline__ void st_scf(float* p, float v){
  asm volatile("global_store_dword %0, %1, off sc0 sc1" :: "v"(p), "v"(v) : "memory");
}

// ---- grid barrier: no agent fences. Cross-block data goes through sc0/sc1
// write-through stores; visibility needs only vmcnt(0) before arrival.
// Consumers use plain cached loads from ring-rotated buffers (RING=32);
// one acquire-inv every 16 ticks clears stale copies before slot reuse.
__device__ __forceinline__ void gbar(unsigned int* slots, unsigned int* flag,
                                     unsigned int ep, int is_master){
  asm volatile("s_waitcnt vmcnt(0)" ::: "memory");
  __syncthreads();
  if (threadIdx.x == 0){
    __hip_atomic_fetch_add(&slots[(blockIdx.x & (NSLOT-1)) * 32], 1u,
                           __ATOMIC_RELAXED, __HIP_MEMORY_SCOPE_AGENT);
  }
  if (is_master){
    if (threadIdx.x < 64){
      for(;;){
        unsigned int v = __hip_atomic_load(&slots[threadIdx.x * 32],
                                           __ATOMIC_RELAXED, __HIP_MEMORY_SCOPE_AGENT);
        int t = (int)v;
        t += __shfl_xor(t, 1);  t += __shfl_xor(t, 2);  t += __shfl_xor(t, 4);
        t += __shfl_xor(t, 8);  t += __shfl_xor(t, 16); t += __shfl_xor(t, 32);
        if ((unsigned int)t >= ep * NBLKS) break;
        __builtin_amdgcn_s_sleep(1);
      }
      __hip_atomic_store(&flag[threadIdx.x * 32], ep,
                         __ATOMIC_RELAXED, __HIP_MEMORY_SCOPE_AGENT);
    }
  } else {
    if (threadIdx.x == 0){
      unsigned int* myf = &flag[(blockIdx.x & (NSLOT-1)) * 32];
      while (__hip_atomic_load(myf, __ATOMIC_RELAXED, __HIP_MEMORY_SCOPE_AGENT) < ep)
        __builtin_amdgcn_s_sleep(2);
    }
  }
  __syncthreads();
  asm volatile("" ::: "memory");
}

// ---------------- prep kernels ----------------

// processed memory, stored TRANSPOSED: pmT[b][h][t]
__global__ void k_pm(const float* __restrict__ enc, const float* __restrict__ ew,
                     const float* __restrict__ eb, unsigned short* __restrict__ pmT){
  int id = blockIdx.x*256 + threadIdx.x;
  if (id >= 64*200*128) return;
  int h = id & 127; int bt = id >> 7;
  const float* er = enc + (size_t)bt*256;
  const float* wr = ew + (size_t)h*256;
  float a0=eb[h], a1=0.f, a2=0.f, a3=0.f;
  for (int k=0;k<256;k+=4){
    a0 += er[k]*wr[k]; a1 += er[k+1]*wr[k+1]; a2 += er[k+2]*wr[k+2]; a3 += er[k+3]*wr[k+3];
  }
  int b = bt / 200, t = bt - b*200;
  pmT[(size_t)b*25600 + (size_t)h*200 + t] = f2b((a0+a1)+(a2+a3));
}

// encoder output, stored TRANSPOSED: encT[b][c][t]
__global__ void k_encT(const float* __restrict__ enc, unsigned short* __restrict__ encT){
  int id = blockIdx.x*256 + threadIdx.x;
  if (id >= 64*256*200) return;
  int t = id % 200; int c = (id / 200) & 255; int b = id / 51200;
  encT[id] = f2b(enc[((size_t)b*200 + t)*256 + c]);
}

__global__ void k_w2f(const float* __restrict__ attw, const float* __restrict__ convw,
                      unsigned short* __restrict__ w2f){
  __shared__ float s_w2[128*31];
  int tid = threadIdx.x;
  for (int i = tid; i < 128*31; i += 256){
    int h = i / 31, k = i % 31;
    float v = 0.f;
    for (int c=0;c<32;++c) v += attw[h*32+c]*convw[c*31+k];
    s_w2[i] = v;
  }
  __syncthreads();
  for (int i = tid; i < 512; i += 256){
    int nt = i >> 6, lane = i & 63;
    int h = nt*16 + (lane&15);
    for (int j=0;j<8;++j){
      int k = (lane>>4)*8 + j;
      w2f[(nt*64+lane)*8+j] = f2b(k < 31 ? s_w2[h*31+k] : 0.f);
    }
  }
}

__global__ void k_packlstm(const float* __restrict__ wih, const float* __restrict__ whh,
                           unsigned short* __restrict__ dst, int Kih, int NKS){
  int id = blockIdx.x*256 + threadIdx.x;
  if (id >= 128*NKS*64) return;
  int lane = id & 63; int t = id >> 6; int cu = t / NKS;
  for (int nt=0; nt<2; ++nt){
    int n = nt*16 + (lane&15);
    int du = n>>2, g = n&3;
    int row = g*1024 + cu*8 + du;
    for (int j=0;j<8;++j){
      int k = (t % NKS)*32 + ((lane>>4)*8) + j;
      float v = (k < Kih) ? wih[(size_t)row*Kih + k] : whh[(size_t)row*1024 + (k - Kih)];
      dst[((size_t)(t*2+nt)*64 + lane)*8 + j] = f2b(v);
    }
  }
}

__global__ void k_bias(const float* bi0,const float* bh0,const float* bi1,const float* bh1,
                       float* b0p, float* b1p){
  int id = blockIdx.x*256 + threadIdx.x;
  if (id >= 4096) return;
  int cu = id>>5, n = id&31, du = n>>2, g = n&3;
  int row = g*1024 + cu*8 + du;
  b0p[id] = bi0[row] + bh0[row];
  b1p[id] = bi1[row] + bh1[row];
}

__global__ void k_packgen(const float* __restrict__ src, unsigned short* __restrict__ dst,
                          int N, int K){
  int tot = (N/16)*(K/32)*64;
  int id = blockIdx.x*256 + threadIdx.x;
  if (id >= tot) return;
  int lane = id & 63; int t = id >> 6;
  int nks = K/32;
  int n = (t / nks)*16 + (lane&15);
  for (int j=0;j<8;++j){
    int k = (t % nks)*32 + (lane>>4)*8 + j;
    dst[((size_t)t*64 + lane)*8 + j] = f2b(src[(size_t)n*K + k]);
  }
}

__global__ void k_woutp(const float* __restrict__ fw, const float* __restrict__ pw,
                        unsigned short* __restrict__ dst){
  int id = blockIdx.x*256 + threadIdx.x;
  if (id >= 11*40*64) return;
  int lane = id & 63; int t = id >> 6;
  int n = (t/40)*16 + (lane&15);
  for (int j=0;j<8;++j){
    int k = (t%40)*32 + (lane>>4)*8 + j;
    float v = 0.f;
    if (n < 160) v = fw[(size_t)n*1280 + k];
    else if (n < 162) v = pw[(size_t)(n-160)*1280 + k];
    dst[((size_t)t*64 + lane)*8 + j] = f2b(v);
  }
}

__global__ void k_pre1(const float* __restrict__ ftgt, const unsigned short* __restrict__ w0p,
                       const float* __restrict__ b0, unsigned short* __restrict__ C1){
  int mt = blockIdx.x;
  int tid = threadIdx.x, w = tid>>6, L = tid&63, ccol = L&15, q = L>>4;
  int sb0 = mt*16; int s = sb0 >> 6; int b0r = sb0 & 63;
  floatx4 z = {0.f,0.f,0.f,0.f};
  floatx4 acc[4] = {z,z,z,z};
  for (int ks=0; ks<5; ++ks){
    ABu av;
    if (s == 0){ av.u4.x=0; av.u4.y=0; av.u4.z=0; av.u4.w=0; }
    else {
      int b = b0r + ccol;
      for (int j=0;j<8;++j){
        int jj = ks*32 + q*8 + j;
        av.us[j] = f2b(ftgt[(size_t)b*80000 + (size_t)(jj%80)*1000 + (size_t)(s-1)*2 + (jj/80)]);
      }
    }
    for (int i=0;i<4;++i){
      ABu bf; bf.u4 = *(const uint4*)(w0p + ((size_t)((w*4+i)*5 + ks)*64 + L)*8);
      acc[i] = MFMA(av.v, bf.v, acc[i]);
    }
  }
  for (int i=0;i<4;++i){
    int icol = (w*4+i)*16 + ccol;
    float bia = b0[icol];
    for (int r=0;r<4;++r){
      int sb = sb0 + q*4 + r;
      C1[(size_t)sb*256 + icol] = f2b(fmaxf(acc[i][r] + bia, 0.f));
    }
  }
}

__global__ void k_pre2(const unsigned short* __restrict__ C1, const unsigned short* __restrict__ w1p,
                       const float* __restrict__ b1, unsigned short* __restrict__ P){
  int mt = blockIdx.x;
  int tid = threadIdx.x, w = tid>>6, L = tid&63, ccol = L&15, q = L>>4;
  int sb0 = mt*16;
  floatx4 z = {0.f,0.f,0.f,0.f};
  floatx4 acc[4] = {z,z,z,z};
  for (int ks=0; ks<8; ++ks){
    ABu av; av.u4 = *(const uint4*)(C1 + (size_t)(sb0+ccol)*256 + ks*32 + q*8);
    for (int i=0;i<4;++i){
      ABu bf; bf.u4 = *(const uint4*)(w1p + ((size_t)((w*4+i)*8 + ks)*64 + L)*8);
      acc[i] = MFMA(av.v, bf.v, acc[i]);
    }
  }
  for (int i=0;i<4;++i){
    int icol = (w*4+i)*16 + ccol;
    float bia = b1[icol];
    for (int r=0;r<4;++r){
      int sb = sb0 + q*4 + r;
      P[(size_t)sb*256 + icol] = f2b(fmaxf(acc[i][r] + bia, 0.f));
    }
  }
}

// ---------------- persistent decoder ----------------
// One barrier per tick; 4-deep software pipeline:
//   tick t: dp(t) | attention(t-1) | LSTM0(t-2) | LSTM1(t-3) | outproj(t-4)
// Block roles: 0-63 att, 64-71 dp, 72-115 outproj, 116-179 LSTM0 (64 cols),
//              180-243 LSTM1 (64 cols), 244-255 idle (255 = barrier master).

struct PArgs {
  const int* tlen;
  const float* ww; const float* wwb; const float* probb;
  const unsigned short* pmT; const unsigned short* encT;
  const unsigned short* W2f; const unsigned short* Wdecf;
  const unsigned short* W0p; const unsigned short* W1p;
  const float* b0p; const float* b1p;
  const unsigned short* P; const unsigned short* Woutp;
  unsigned short* xh0; unsigned short* xh1; unsigned short* acbf;
  float* dpbuf;
  unsigned int* bar; unsigned int* flag;
  float* dout;
};

__global__ __launch_bounds__(256, 1) void k_decoder(PArgs A)
{
  const int cu = blockIdx.x;
  const int tid = threadIdx.x;
  const int w = tid>>6, L = tid&63;
  const int ccol = L&15, q = L>>4;
  const int is_master = (cu == NBLKS-1);

  const int R_ATT = (cu < 64);
  const int R_DP  = (cu >= 64 && cu < 72);
  const int R_OUT = (cu >= 72 && cu < 116);
  const int R_L0  = (cu >= 116 && cu < 180);
  const int R_L1  = (cu >= 180 && cu < 244);

  extern __shared__ char pool[];
  // role-specific dynamic LDS layout
  unsigned short* sW   = (unsigned short*)pool;          // L0 98304 / L1 131072 / dp 131072 / out 40960
  float* sGB = nullptr; float* sCST = nullptr; float* sBIAS = nullptr; float* sRED = nullptr;
  if (R_L0){ sGB = (float*)(pool + 98304);  sCST = (float*)(pool + 114944); sBIAS = (float*)(pool + 119040); }
  if (R_L1){ sGB = (float*)(pool + 131072); sCST = (float*)(pool + 147712); sBIAS = (float*)(pool + 151808); }
  if (R_OUT){ sRED = (float*)(pool + 40960); }

  __shared__ unsigned short s_ahi[240], s_alo[240];
  __shared__ float s_e[256];
  __shared__ float s_red[16];
  __shared__ float s_ww[128];

  // ---- per-role init ----
  const int g0 = cu - 116;   // LSTM0 block id (0..63)
  const int g1 = cu - 180;   // LSTM1 block id (0..63)
  const int dpid = cu - 64;  // dp block id (0..7)
  const int dmg = dpid >> 1, dng = dpid & 1;
  const int oid = cu - 72;   // outproj id (0..43)
  const int ont = oid % 11, omg = oid / 11;

  if (R_L0){
    const unsigned short* src = A.W0p + (size_t)(2*g0)*49152;
    for (int i = tid*8; i < 49152; i += 2048)
      *(uint4*)(sW + i) = *(const uint4*)(src + i);
    if (tid < 64) sBIAS[tid] = A.b0p[g0*64 + tid];
    for (int i = tid; i < 1024; i += 256) sCST[i] = 0.f;
  }
  if (R_L1){
    const unsigned short* src = A.W1p + (size_t)(2*g1)*65536;
    for (int i = tid*8; i < 65536; i += 2048)
      *(uint4*)(sW + i) = *(const uint4*)(src + i);
    if (tid < 64) sBIAS[tid] = A.b1p[g1*64 + tid];
    for (int i = tid; i < 1024; i += 256) sCST[i] = 0.f;
  }
  if (R_DP){
    const unsigned short* src = A.Wdecf + (size_t)dng*4*32*512;
    for (int i = tid*8; i < 65536; i += 2048)
      *(uint4*)(sW + i) = *(const uint4*)(src + i);
  }
  if (R_OUT){
    const unsigned short* src = A.Woutp + (size_t)ont*40*512;
    for (int i = tid*8; i < 40*512; i += 2048)
      *(uint4*)(sW + i) = *(const uint4*)(src + i);
  }

  float accv = 0.f; int lenb = 0; float wwbv = 0.f;
  ABu w2fr[8];
  if (R_ATT) {
    lenb = A.tlen[cu];
    wwbv = A.wwb[0];
    float inv = 1.f / (float)lenb;
    for (int i = tid; i < 240; i += 256) {
      int t = i - 15;
      float v = (t >= 0 && t < 200 && t < lenb) ? inv : 0.f;
      unsigned short hi = f2b(v);
      s_ahi[i] = hi; s_alo[i] = f2b(v - b2f(hi));
    }
    if (tid < 200) accv = (tid < lenb) ? inv : 0.f;
    if (tid < 128) s_ww[tid] = A.ww[tid];
    #pragma unroll
    for (int nt=0; nt<8; ++nt) w2fr[nt].u4 = *(const uint4*)(A.W2f + (nt*64 + L)*8);
  }

  unsigned int ep = 0;
  gbar(A.bar, A.flag, ++ep, is_master);
  __builtin_amdgcn_fence(__ATOMIC_ACQUIRE, "agent");  // one-time clean slate

  for (int tick = 0; tick <= SS+3; ++tick) {
    const int s_att = tick - 1;
    const int s_l0  = tick - 2;
    const int s_l1  = tick - 3;
    const int s_p   = tick - 4;

    // ======== pre-barrier prologues (PRECOMPUTED operands only) ========
    // Their load latency is absorbed by the barrier's vmcnt(0) wait.
    uint4 pA[8], pW2[8], pW3[8];
    const unsigned short *l0AC = nullptr, *l0P = nullptr, *l0H = nullptr;
    const unsigned short *l1A = nullptr, *l1B = nullptr;
    const unsigned short *Wst = nullptr;
    const int l0_act = R_L0 && (s_l0 >= 0 && s_l0 < SS);
    const int l1_act = R_L1 && (s_l1 >= 0 && s_l1 < SS);
    if (l0_act){
      l0AC = A.acbf + (size_t)(s_l0&(RING-1))*16384;
      l0P  = A.P + (size_t)s_l0*16384;
      l0H  = A.xh0 + (size_t)((s_l0+RING-1)&(RING-1))*65536;
      Wst  = A.W0p + (size_t)(2*g0+1)*49152;
      const int brow = w*16 + ccol;
      #pragma unroll
      for (int t=0;t<8;++t){
        pA[t]  = *(const uint4*)(l0P + (size_t)brow*256 + t*32 + q*8);
        int ow = 8+t;
        pW2[t] = *(const uint4*)(Wst + (size_t)(ow*2+0)*512 + L*8);
        pW3[t] = *(const uint4*)(Wst + (size_t)(ow*2+1)*512 + L*8);
      }
    }
    if (l1_act){
      l1A = A.xh0 + (size_t)(s_l1&(RING-1))*65536;
      l1B = A.xh1 + (size_t)((s_l1+RING-1)&(RING-1))*65536;
      Wst = A.W1p + (size_t)(2*g1+1)*65536;
      #pragma unroll
      for (int t=0;t<8;++t){
        pW2[t] = *(const uint4*)(Wst + (size_t)(t*2+0)*512 + L*8);
        pW3[t] = *(const uint4*)(Wst + (size_t)(t*2+1)*512 + L*8);
      }
    }

    gbar(A.bar, A.flag, ++ep, is_master);

    // ================= ATTENTION (s_att) =================
    if (R_ATT && s_att >= 0 && s_att < SS) {
      const int b = cu;
      const int slot = s_att & (RING-1);
      // dp values for my lanes (h = nt*16+ccol) — registers, no LDS round-trip
      float dpv[8];
      {
        const float* dpp = A.dpbuf + (size_t)slot*8192 + b*128 + ccol;
        #pragma unroll
        for (int nt=0;nt<8;++nt) dpv[nt] = dpp[nt*16];
      }
      // pmT prefetch for all my mt's (hidden under conv MFMA)
      USu pv[4][8];
      #pragma unroll
      for (int i=0;i<4;++i){
        int mt = w + i*4;
        if (mt < 13){
          int t0 = mt*16 + q*4;
          #pragma unroll
          for (int nt=0;nt<8;++nt)
            pv[i][nt].v = *(const ushort4*)(A.pmT + (size_t)b*25600 + (size_t)(nt*16+ccol)*200 + t0);
        }
      }
      // conv (MFMA hi/lo) + scores
      #pragma unroll
      for (int i=0;i<4;++i){
        int mt = w + i*4;
        if (mt >= 13) continue;
        ABu ahi, alo;
        int abase = mt*16 + ccol + q*8;
        #pragma unroll
        for (int j=0;j<8;++j){ ahi.us[j] = s_ahi[abase+j]; alo.us[j] = s_alo[abase+j]; }
        floatx4 acc[8];
        #pragma unroll
        for (int nt=0;nt<8;++nt){
          floatx4 zz = {0.f,0.f,0.f,0.f};
          zz = MFMA(ahi.v, w2fr[nt].v, zz);
          zz = MFMA(alo.v, w2fr[nt].v, zz);
          acc[nt] = zz;
        }
        int t0 = mt*16 + q*4;
        #pragma unroll
        for (int r=0;r<4;++r){
          int t = t0 + r;
          float part = 0.f;
          if (t < 200) {
            #pragma unroll
            for (int nt=0;nt<8;++nt){
              int h = nt*16 + ccol;
              float v = acc[nt][r] + b2f(pv[i][nt].us[r]) + dpv[nt];
              part += s_ww[h] * tanhf_fast(v);
            }
          }
          part += __shfl_xor(part, 1);
          part += __shfl_xor(part, 2);
          part += __shfl_xor(part, 4);
          part += __shfl_xor(part, 8);
          if (t < 200 && ccol == 0)
            s_e[t] = (t < lenb) ? (part + wwbv) : -1e30f;
        }
      }
      __syncthreads();
      // softmax + acc update
      {
        float v = (tid < 200) ? s_e[tid] : -1e30f;
        float m = v;
        for (int o=1;o<64;o<<=1) m = fmaxf(m, __shfl_xor(m, o));
        if (L == 0) s_red[w] = m;
        __syncthreads();
        m = fmaxf(fmaxf(s_red[0], s_red[1]), fmaxf(s_red[2], s_red[3]));
        float ex = (tid < 200) ? __expf(v - m) : 0.f;
        float sm = ex;
        for (int o=1;o<64;o<<=1) sm += __shfl_xor(sm, o);
        if (L == 0) s_red[8+w] = sm;
        __syncthreads();
        float inv = 1.f / (s_red[8]+s_red[9]+s_red[10]+s_red[11]);
        if (tid < 200){
          float aw = ex * inv;
          s_e[tid] = aw;
          A.dout[5184000 + (size_t)b*100000 + (size_t)s_att*200 + tid] = aw;
          accv = (s_att == 0) ? aw : (accv + aw);
          unsigned short hi = f2b(accv);
          s_ahi[15+tid] = hi; s_alo[15+tid] = f2b(accv - b2f(hi));
        }
      }
      __syncthreads();
      // ac[c] = sum_t aw[t]*encT[b,c,t]
      {
        const unsigned short* er = A.encT + (size_t)b*51200 + (size_t)tid*200;
        float a0=0.f,a1=0.f,a2=0.f,a3=0.f;
        #pragma unroll 5
        for (int it=0; it<25; ++it){
          ABu v; v.u4 = *(const uint4*)(er + it*8);
          a0 += s_e[it*8+0]*b2f(v.us[0]); a1 += s_e[it*8+1]*b2f(v.us[1]);
          a2 += s_e[it*8+2]*b2f(v.us[2]); a3 += s_e[it*8+3]*b2f(v.us[3]);
          a0 += s_e[it*8+4]*b2f(v.us[4]); a1 += s_e[it*8+5]*b2f(v.us[5]);
          a2 += s_e[it*8+6]*b2f(v.us[6]); a3 += s_e[it*8+7]*b2f(v.us[7]);
        }
        st_sc(A.acbf + (size_t)slot*16384 + b*256 + tid, f2b((a0+a1)+(a2+a3)));
      }
    }

    // ================= DP (tick) : dp = h0(tick-1) @ Wdec^T =================
    if (R_DP && tick < SS) {
      const unsigned short* h0r = A.xh0 + (size_t)((tick+RING-1)&(RING-1))*65536;
      const int brow = dmg*16 + ccol;
      uint4 pd[16];
      #pragma unroll
      for (int t=0;t<16;++t) pd[t] = *(const uint4*)(h0r + (size_t)brow*1024 + t*32 + q*8);
      floatx4 acc = {0.f,0.f,0.f,0.f};
      #pragma unroll
      for (int ks=0; ks<32; ++ks){
        ABu av; av.u4 = pd[ks&15];
        ABu bf; bf.u4 = *(const uint4*)(sW + (size_t)(w*32+ks)*512 + L*8);
        if (ks+16 < 32) pd[ks&15] = *(const uint4*)(h0r + (size_t)brow*1024 + (ks+16)*32 + q*8);
        acc = MFMA(av.v, bf.v, acc);
      }
      float* dpo = A.dpbuf + (size_t)(tick&(RING-1))*8192;
      #pragma unroll
      for (int r=0;r<4;++r){
        int b = dmg*16 + q*4 + r;
        int col = dng*64 + w*16 + ccol;
        st_scf(dpo + (size_t)b*128 + col, acc[r]);
      }
    }

    // ================= OUTPROJ (s_p) =================
    if (R_OUT && s_p >= 0 && s_p < SS) {
      const unsigned short* segH  = A.xh1 + (size_t)(s_p&(RING-1))*65536;
      const unsigned short* segAC = A.acbf + (size_t)(s_p&(RING-1))*16384;
      const int brow = omg*16 + ccol;
      uint4 ap[10];
      #pragma unroll
      for (int kk=0; kk<10; ++kk){
        int ks = w*10 + kk;
        ap[kk] = *(const uint4*)((ks < 32) ? (segH + (size_t)brow*1024 + ks*32 + q*8)
                                           : (segAC + (size_t)brow*256 + (ks-32)*32 + q*8));
      }
      floatx4 acc = {0.f,0.f,0.f,0.f};
      #pragma unroll
      for (int kk=0; kk<10; ++kk){
        ABu av, bf; av.u4 = ap[kk];
        bf.u4 = *(const uint4*)(sW + (size_t)(w*10+kk)*512 + L*8);
        acc = MFMA(av.v, bf.v, acc);
      }
      #pragma unroll
      for (int r=0;r<4;++r) sRED[w*256 + (q*4+r)*16 + ccol] = acc[r];
      __syncthreads();
      {
        float v = sRED[tid] + sRED[256+tid] + sRED[512+tid] + sRED[768+tid];
        int blocal = tid>>4, colp = tid&15;
        int j = ont*16 + colp; int bb = omg*16 + blocal;
        if (j < 160){
          int rr = j/80, cc2 = j%80;
          A.dout[(size_t)bb*80000 + (size_t)cc2*1000 + s_p*2 + rr] = v;
        } else if (j < 162){
          A.dout[5120000 + (size_t)bb*1000 + s_p*2 + (j-160)] = v + A.probb[j-160];
        }
      }
    }

    // ================= LSTM0 (s_l0) : 64 cols/block =================
    if (l0_act) {
      const int brow = w*16 + ccol;
      floatx4 a0 = {0.f,0.f,0.f,0.f}, a1 = a0, a2 = a0, a3 = a0;
      // K-order: P (t 0..7), h0 (8..39), ac (40..47); ow = t<40 ? t+8 : t-40
      #pragma unroll
      for (int t=0;t<48;++t){
        ABu av; av.u4 = pA[t&7];
        int ow = (t < 40) ? (t+8) : (t-40);
        ABu b0f, b1f, b2f_, b3f;
        b0f.u4 = *(const uint4*)(sW + (size_t)(ow*2+0)*512 + L*8);
        b1f.u4 = *(const uint4*)(sW + (size_t)(ow*2+1)*512 + L*8);
        b2f_.u4 = pW2[t&7]; b3f.u4 = pW3[t&7];
        if (t+8 < 48){
          int t2 = t+8;
          const unsigned short* sp = (t2 < 40) ? (l0H + (size_t)brow*1024 + (t2-8)*32 + q*8)
                                               : (l0AC + (size_t)brow*256 + (t2-40)*32 + q*8);
          pA[t&7] = *(const uint4*)sp;
          int ow2 = (t2 < 40) ? (t2+8) : (t2-40);
          pW2[t&7] = *(const uint4*)(Wst + (size_t)(ow2*2+0)*512 + L*8);
          pW3[t&7] = *(const uint4*)(Wst + (size_t)(ow2*2+1)*512 + L*8);
        }
        a0 = MFMA(av.v, b0f.v, a0);
        a1 = MFMA(av.v, b1f.v, a1);
        a2 = MFMA(av.v, b2f_.v, a2);
        a3 = MFMA(av.v, b3f.v, a3);
      }
      #pragma unroll
      for (int r=0;r<4;++r){
        int bb = w*16 + q*4 + r;
        sGB[bb*65 +      ccol] = a0[r] + sBIAS[ccol];
        sGB[bb*65 + 16 + ccol] = a1[r] + sBIAS[16+ccol];
        sGB[bb*65 + 32 + ccol] = a2[r] + sBIAS[32+ccol];
        sGB[bb*65 + 48 + ccol] = a3[r] + sBIAS[48+ccol];
      }
      __syncthreads();
      unsigned short* xout = A.xh0 + (size_t)(s_l0&(RING-1))*65536;
      #pragma unroll
      for (int rep=0;rep<4;++rep){
        int cell = tid + rep*256;
        int du = cell>>6, bb = cell&63;
        int cb = (du>>3)*32 + (du&7)*4;
        float gi=sGB[bb*65+cb+0], gf=sGB[bb*65+cb+1];
        float gg=sGB[bb*65+cb+2], go=sGB[bb*65+cb+3];
        float cprev = sCST[du*64+bb];
        float c2 = sigf(gf)*cprev + sigf(gi)*tanhf_fast(gg);
        float h2 = sigf(go)*tanhf_fast(c2);
        float cn = 0.1f*cprev + 0.9f*c2;
        float hp = b2f(l0H[(size_t)bb*1024 + g0*16 + du]);
        float hn = 0.1f*hp + 0.9f*h2;
        sCST[du*64+bb] = cn;
        st_sc(xout + (size_t)bb*1024 + g0*16 + du, f2b(hn));
      }
    }

    // ================= LSTM1 (s_l1) : 64 cols/block =================
    if (l1_act) {
      const int brow = w*16 + ccol;
      // A prologue (ring data — only safe AFTER the barrier)
      #pragma unroll
      for (int t=0;t<8;++t)
        pA[t] = *(const uint4*)(l1A + (size_t)brow*1024 + t*32 + q*8);
      floatx4 a0 = {0.f,0.f,0.f,0.f}, a1 = a0, a2 = a0, a3 = a0;
      #pragma unroll
      for (int t=0;t<64;++t){
        ABu av; av.u4 = pA[t&7];
        ABu b0f, b1f, b2f_, b3f;
        b0f.u4 = *(const uint4*)(sW + (size_t)(t*2+0)*512 + L*8);
        b1f.u4 = *(const uint4*)(sW + (size_t)(t*2+1)*512 + L*8);
        b2f_.u4 = pW2[t&7]; b3f.u4 = pW3[t&7];
        if (t+8 < 64){
          int t2 = t+8;
          const unsigned short* sp = (t2 < 32) ? (l1A + (size_t)brow*1024 + t2*32 + q*8)
                                               : (l1B + (size_t)brow*1024 + (t2-32)*32 + q*8);
          pA[t&7] = *(const uint4*)sp;
          pW2[t&7] = *(const uint4*)(Wst + (size_t)(t2*2+0)*512 + L*8);
          pW3[t&7] = *(const uint4*)(Wst + (size_t)(t2*2+1)*512 + L*8);
        }
        a0 = MFMA(av.v, b0f.v, a0);
        a1 = MFMA(av.v, b1f.v, a1);
        a2 = MFMA(av.v, b2f_.v, a2);
        a3 = MFMA(av.v, b3f.v, a3);
      }
      #pragma unroll
      for (int r=0;r<4;++r){
        int bb = w*16 + q*4 + r;
        sGB[bb*65 +      ccol] = a0[r] + sBIAS[ccol];
        sGB[bb*65 + 16 + ccol] = a1[r] + sBIAS[16+ccol];
        sGB[bb*65 + 32 + ccol] = a2[r] + sBIAS[32+ccol];
        sGB[bb*65 + 48 + ccol] = a3[r] + sBIAS[48+ccol];
      }
      __syncthreads();
      unsigned short* xout = A.xh1 + (size_t)(s_l1&(RING-1))*65536;
      #pragma unroll
      for (int rep=0;rep<4;++rep){
        int cell = tid + rep*256;
        int du = cell>>6, bb = cell&63;
        int cb = (du>>3)*32 + (du&7)*4;
        float gi=sGB[bb*65+cb+0], gf=sGB[bb*65+cb+1];
        float gg=sGB[bb*65+cb+2], go=sGB[bb*65+cb+3];
        float cprev = sCST[du*64+bb];
        float c2 = sigf(gf)*cprev + sigf(gi)*tanhf_fast(gg);
        float h2 = sigf(go)*tanhf_fast(c2);
        float cn = 0.1f*cprev + 0.9f*c2;
        float hp = b2f(l1B[(size_t)bb*1024 + g1*16 + du]);
        float hn = 0.1f*hp + 0.9f*h2;
        sCST[du*64+bb] = cn;
        st_sc(xout + (size_t)bb*1024 + g1*16 + du, f2b(hn));
      }
    }

    // ring hygiene: RING=32 slots; content read ≤4 ticks after write, slot
    // rewritten after 32. One acquire-inv per 16 ticks covers every window.
    if ((tick & 15) == 8) __builtin_amdgcn_fence(__ATOMIC_ACQUIRE, "agent");
  }
}

// ---------------- host launcher ----------------

extern "C" void kernel_launch(void* const* d_in, const int* in_sizes, int n_in,
                              void* d_out, int out_size, void* d_ws, size_t ws_size,
                              hipStream_t stream)
{
  const float* enc   = (const float*)d_in[0];
  const int*   tlen  = (const int*)d_in[1];
  const float* ftgt  = (const float*)d_in[2];
  const float* aew   = (const float*)d_in[3];
  const float* aeb   = (const float*)d_in[4];
  const float* adw   = (const float*)d_in[5];
  const float* aaw   = (const float*)d_in[6];
  const float* acw   = (const float*)d_in[7];
  const float* aww   = (const float*)d_in[8];
  const float* awb   = (const float*)d_in[9];
  const float* pw0   = (const float*)d_in[10];
  const float* pb0   = (const float*)d_in[11];
  const float* pw1   = (const float*)d_in[12];
  const float* pb1   = (const float*)d_in[13];
  const float* l0wih = (const float*)d_in[14];
  const float* l0whh = (const float*)d_in[15];
  const float* l0bih = (const float*)d_in[16];
  const float* l0bhh = (const float*)d_in[17];
  const float* l1wih = (const float*)d_in[18];
  const float* l1whh = (const float*)d_in[19];
  const float* l1bih = (const float*)d_in[20];
  const float* l1bhh = (const float*)d_in[21];
  const float* fow   = (const float*)d_in[22];
  const float* pow_  = (const float*)d_in[23];
  const float* pob   = (const float*)d_in[24];
  float* dout = (float*)d_out;

  char* ws = (char*)d_ws;
  size_t off = 0;
  auto alloc = [&](size_t bytes)->void*{
    void* p = (void*)(ws + off);
    off += (bytes + 255) & ~(size_t)255;
    return p;
  };

  unsigned short* pmT   = (unsigned short*)alloc((size_t)64*200*128*2 + 256);
  unsigned short* encT  = (unsigned short*)alloc((size_t)64*256*200*2);
  unsigned short* W2f   = (unsigned short*)alloc((size_t)8*64*8*2);
  unsigned short* Wdecf = (unsigned short*)alloc((size_t)8*32*64*8*2);
  unsigned short* W0p   = (unsigned short*)alloc((size_t)128*48*2*512*2);
  unsigned short* W1p   = (unsigned short*)alloc((size_t)128*64*2*512*2);
  float* b0p            = (float*)alloc((size_t)4096*4);
  float* b1p            = (float*)alloc((size_t)4096*4);
  unsigned short* w0pp  = (unsigned short*)alloc((size_t)16*5*512*2);
  unsigned short* w1pp  = (unsigned short*)alloc((size_t)16*8*512*2);
  unsigned short* C1    = (unsigned short*)alloc((size_t)32000*256*2);
  unsigned short* P     = (unsigned short*)alloc((size_t)32000*256*2);
  unsigned short* Woutp = (unsigned short*)alloc((size_t)11*40*512*2);
  unsigned short* xh0   = (unsigned short*)alloc((size_t)RING*65536*2);
  unsigned short* xh1   = (unsigned short*)alloc((size_t)RING*65536*2);
  unsigned short* acbf  = (unsigned short*)alloc((size_t)RING*16384*2);
  float* dpbuf          = (float*)alloc((size_t)RING*8192*4);
  unsigned int* bar     = (unsigned int*)alloc((size_t)NSLOT*128);
  unsigned int* flag    = (unsigned int*)alloc((size_t)NSLOT*128);

  hipMemsetAsync(bar, 0, (size_t)NSLOT*128, stream);
  hipMemsetAsync(flag, 0, (size_t)NSLOT*128, stream);
  hipMemsetAsync(xh0, 0, (size_t)RING*65536*2, stream);
  hipMemsetAsync(xh1, 0, (size_t)RING*65536*2, stream);
  hipMemsetAsync(acbf, 0, (size_t)RING*16384*2, stream);

  k_pm     <<<6400, 256, 0, stream>>>(enc, aew, aeb, pmT);
  k_encT   <<<12800,256, 0, stream>>>(enc, encT);
  k_w2f    <<<1,    256, 0, stream>>>(aaw, acw, W2f);
  k_packgen<<<64,   256, 0, stream>>>(adw, Wdecf, 128, 1024);
  k_packlstm<<<1536,256, 0, stream>>>(l0wih, l0whh, W0p, 512, 48);
  k_packlstm<<<2048,256, 0, stream>>>(l1wih, l1whh, W1p, 1024, 64);
  k_bias   <<<16,   256, 0, stream>>>(l0bih, l0bhh, l1bih, l1bhh, b0p, b1p);
  k_packgen<<<20,   256, 0, stream>>>(pw0, w0pp, 256, 160);
  k_packgen<<<32,   256, 0, stream>>>(pw1, w1pp, 256, 256);
  k_woutp  <<<110,  256, 0, stream>>>(fow, pow_, Woutp);
  k_pre1   <<<2000, 256, 0, stream>>>(ftgt, w0pp, pb0, C1);
  k_pre2   <<<2000, 256, 0, stream>>>(C1, w1pp, pb1, P);

  PArgs A;
  A.tlen = tlen; A.ww = aww; A.wwb = awb; A.probb = pob;
  A.pmT = pmT; A.encT = encT; A.W2f = W2f; A.Wdecf = Wdecf;
  A.W0p = W0p; A.W1p = W1p; A.b0p = b0p; A.b1p = b1p;
  A.P = P; A.Woutp = Woutp;
  A.xh0 = xh0; A.xh1 = xh1; A.acbf = acbf; A.dpbuf = dpbuf;
  A.bar = bar; A.flag = flag; A.dout = dout;

  hipFuncSetAttribute((const void*)k_decoder,
                      hipFuncAttributeMaxDynamicSharedMemorySize, DYN_LDS);
  k_decoder<<<NBLKS, 256, DYN_LDS, stream>>>(A);
}